// Round 13
// baseline (311.607 us; speedup 1.0000x reference)
//
#include <hip/hip_runtime.h>
#include <hip/hip_bf16.h>

// Problem constants (MultiTaskFEGIN): N=100000, E=1200000, F=32, H=64, L=3,
// G=256, C=200000, NC=10, D=L*H=192.

#define GG 256
#define NCC 10
#define DD 192
#define BSH 8          // bucket shift: 256 nodes/bucket (NB <= 512 for N <= 131072)

typedef short bf16x8 __attribute__((ext_vector_type(8)));
typedef float f32x4  __attribute__((ext_vector_type(4)));

__device__ inline unsigned short f2bf_u(float x) {
    __hip_bfloat16 h = __float2bfloat16(x);
    return *reinterpret_cast<unsigned short*>(&h);
}
__device__ inline float bf2f(unsigned short u) {
    return __uint_as_float(((unsigned int)u) << 16);
}

// ---------------------------------------------------------------------------
// Binned CSR build: packed (src<<BSH)|dst_local ints (half the scatter bytes);
// contiguous per-bucket regions -> full-line fills.
// ---------------------------------------------------------------------------
__global__ void bin_hist(const int* __restrict__ dst, int* __restrict__ bcnt, int E_) {
    __shared__ int h[512];
    const int t = threadIdx.x;
    h[t] = 0; h[t + 256] = 0;
    __syncthreads();
    for (int e = blockIdx.x * 256 + t; e < E_; e += gridDim.x * 256)
        atomicAdd(&h[dst[e] >> BSH], 1);
    __syncthreads();
    if (h[t]) atomicAdd(&bcnt[t], h[t]);
    if (h[t + 256]) atomicAdd(&bcnt[t + 256], h[t + 256]);
}

__global__ void bin_scan(const int* __restrict__ bcnt, int* __restrict__ bbase,
                         int* __restrict__ bpos, int NB, int E_) {
    __shared__ int ps[256];
    const int t = threadIdx.x;
    int v0 = (2 * t < NB) ? bcnt[2 * t] : 0;
    int v1 = (2 * t + 1 < NB) ? bcnt[2 * t + 1] : 0;
    int pv = v0 + v1;
    ps[t] = pv;
    __syncthreads();
    for (int off = 1; off < 256; off <<= 1) {
        int x = (t >= off) ? ps[t - off] : 0;
        __syncthreads();
        ps[t] += x;
        __syncthreads();
    }
    const int excl = ps[t] - pv;
    if (2 * t < NB)     { bbase[2 * t] = excl;          bpos[2 * t] = excl; }
    if (2 * t + 1 < NB) { bbase[2 * t + 1] = excl + v0; bpos[2 * t + 1] = excl + v0; }
    if (t == 0) bbase[NB] = E_;
}

// 4096 edges/block (16/thread): rank in LDS, one range-claim per bucket,
// packed 4B scatter writes in ~84B contiguous runs.
__global__ __launch_bounds__(256) void bin_scatter(
    const int* __restrict__ src, const int* __restrict__ dst,
    int* __restrict__ bpos, unsigned* __restrict__ ebuf, int E_) {
    __shared__ int h[512];
    __shared__ int base[512];
    const int t = threadIdx.x;
    const int e0 = blockIdx.x * 4096;
    h[t] = 0; h[t + 256] = 0;
    __syncthreads();
    int myb[16], myr[16];
    unsigned pk[16];
    #pragma unroll
    for (int u = 0; u < 16; ++u) {
        int e = e0 + t + u * 256;
        if (e < E_) {
            int d = dst[e];
            myb[u] = d >> BSH;
            pk[u] = ((unsigned)src[e] << BSH) | (unsigned)(d & ((1 << BSH) - 1));
            myr[u] = atomicAdd(&h[myb[u]], 1);
        } else myb[u] = -1;
    }
    __syncthreads();
    if (h[t]) base[t] = atomicAdd(&bpos[t], h[t]);
    if (h[t + 256]) base[t + 256] = atomicAdd(&bpos[t + 256], h[t + 256]);
    __syncthreads();
    #pragma unroll
    for (int u = 0; u < 16; ++u)
        if (myb[u] >= 0)
            ebuf[base[myb[u]] + myr[u]] = pk[u];
}

// One block per 256-node bucket: local histogram -> scan -> rowptr -> nbr.
__global__ __launch_bounds__(256) void csr_bucket(
    const unsigned* __restrict__ ebuf, const int* __restrict__ bbase,
    int* __restrict__ rowptr, int* __restrict__ nbr, int N_, int NB) {
    __shared__ int lh[256];
    __shared__ int lx[256];
    __shared__ int ps[256];
    const int b = blockIdx.x;
    const int t = threadIdx.x;
    const int ebase = bbase[b], eend = bbase[b + 1];
    const int ecnt = eend - ebase;
    const int n0 = b << BSH;

    lh[t] = 0;
    __syncthreads();
    for (int i = t; i < ecnt; i += 256)
        atomicAdd(&lh[ebuf[ebase + i] & ((1 << BSH) - 1)], 1);
    __syncthreads();

    int v = lh[t];
    ps[t] = v;
    __syncthreads();
    for (int off = 1; off < 256; off <<= 1) {
        int x = (t >= off) ? ps[t - off] : 0;
        __syncthreads();
        ps[t] += x;
        __syncthreads();
    }
    lx[t] = ps[t] - v;
    {
        int n = n0 + t;
        if (n < N_) rowptr[n] = ebase + lx[t];
    }
    if (b == NB - 1 && t == 0) rowptr[N_] = eend;
    __syncthreads();
    lh[t] = lx[t];
    __syncthreads();
    for (int i = t; i < ecnt; i += 256) {
        unsigned p = ebuf[ebase + i];
        int r = atomicAdd(&lh[p & ((1 << BSH) - 1)], 1);
        nbr[ebase + r] = (int)(p >> BSH);
    }
}

// ---------------------------------------------------------------------------
// x2b: x [N][32] fp32 -> bf16 (64B gather rows, slice L2-friendly).
// ---------------------------------------------------------------------------
__global__ void x2b_kernel(const float* __restrict__ x, unsigned short* __restrict__ xb,
                           int n_elem) {
    int i = blockIdx.x * 256 + threadIdx.x;
    int stride = gridDim.x * 256;
    for (; i * 4 < n_elem; i += stride) {
        float4 v = *(const float4*)(x + i * 4);
        ushort4 u;
        u.x = f2bf_u(v.x); u.y = f2bf_u(v.y); u.z = f2bf_u(v.z); u.w = f2bf_u(v.w);
        *(ushort4*)(xb + i * 4) = u;
    }
}

// ---------------------------------------------------------------------------
// prep_enc: pack the 6 encoder weight matrices into MFMA B-fragment bf16.
// ---------------------------------------------------------------------------
__global__ void prep_enc(const float* __restrict__ c1W1, const float* __restrict__ c1W2,
                         const float* __restrict__ csW1, const float* __restrict__ csW2,
                         unsigned short* __restrict__ enc) {
    int idx = blockIdx.x * 256 + threadIdx.x;
    if (idx >= 22528) return;
    const float* W; int rel;
    if (idx < 2048)       { W = c1W1;        rel = idx; }
    else if (idx < 6144)  { W = c1W2;        rel = idx - 2048; }
    else if (idx < 10240) { W = csW1;        rel = idx - 6144; }
    else if (idx < 14336) { W = csW2;        rel = idx - 10240; }
    else if (idx < 18432) { W = csW1 + 4096; rel = idx - 14336; }
    else                  { W = csW2 + 4096; rel = idx - 18432; }
    int frag = rel >> 9;
    int lane = (rel >> 3) & 63;
    int j = rel & 7;
    int ks = frag >> 2, nt = frag & 3;
    int k = ks * 32 + ((lane >> 4) << 3) + j;
    int n = nt * 16 + (lane & 15);
    enc[idx] = f2bf_u(W[k * 64 + n]);
}

// ---------------------------------------------------------------------------
// gcnt by binary search (batch sorted).
// ---------------------------------------------------------------------------
__global__ void gcnt_bs(const int* __restrict__ batch, int* __restrict__ gcnt_i, int N_) {
    __shared__ int lbs[GG + 1];
    const int g = threadIdx.x;
    int lo = 0, hi = N_;
    while (lo < hi) {
        int mid = (lo + hi) >> 1;
        if (batch[mid] < g) lo = mid + 1; else hi = mid;
    }
    lbs[g] = lo;
    if (g == 0) lbs[GG] = N_;
    __syncthreads();
    gcnt_i[g] = lbs[g + 1] - lbs[g];
}

// ---------------------------------------------------------------------------
// Fused GIN layer: 3-deep pipelined running-sum gather -> MFMA MLP -> BN ->
// hb slice + fused pool. Unified K=32/64: all 64 lanes read element
// lane&(K-1) of each row (K=32: upper half redundant, writes guarded).
// Loads for chunk k+2 issue before accumulating chunk k (~48 values in
// flight/wave); idx prefetched 3 chunks ahead. Boundaries via per-chunk
// uniform-branch prefix fixups. nbr padded >=128 zeroed ints past E.
// ---------------------------------------------------------------------------
#define SWZ(row, byte) ((byte) ^ (((row) & 7) << 4))

#define GSTEP(VCUR, VNXT)                                                     \
    _Pragma("unroll")                                                         \
    for (int u = 0; u < 16; ++u)                                              \
        VNXT[u] = bf2f(*(const unsigned short*)(hbase + (unsigned)idx[u] * (unsigned)RSB + lane2)); \
    _Pragma("unroll")                                                         \
    for (int u = 0; u < 16; ++u) idx[u] = nbp[k + 48 + u];                    \
    {                                                                         \
        float runk = run;                                                     \
        _Pragma("unroll")                                                     \
        for (int u = 0; u < 16; ++u) run += VCUR[u];                          \
        if ((unsigned)(e1 - k) < 16u) { float tt = runk;                      \
            _Pragma("unroll")                                                 \
            for (int u = 0; u < 16; ++u) tt += (u < e1 - k) ? VCUR[u] : 0.f;  \
            s0 = tt; }                                                        \
        if ((unsigned)(e2 - k) < 16u) { float tt = runk;                      \
            _Pragma("unroll")                                                 \
            for (int u = 0; u < 16; ++u) tt += (u < e2 - k) ? VCUR[u] : 0.f;  \
            s1 = tt; }                                                        \
        if ((unsigned)(e3 - k) < 16u) { float tt = runk;                      \
            _Pragma("unroll")                                                 \
            for (int u = 0; u < 16; ++u) tt += (u < e3 - k) ? VCUR[u] : 0.f;  \
            s2 = tt; }                                                        \
        if ((unsigned)(cnt - k) < 16u) { float tt = runk;                     \
            _Pragma("unroll")                                                 \
            for (int u = 0; u < 16; ++u) tt += (u < cnt - k) ? VCUR[u] : 0.f; \
            s3 = tt; }                                                        \
    }                                                                         \
    k += 16;                                                                  \
    if (k > cnt) break;

template<int K>
__global__ __launch_bounds__(512) void gin_fused(
    const unsigned short* __restrict__ hin_b,  // bf16 rows: stride DD (K=64) / 32 (K=32)
    const int* __restrict__ rowptr, const int* __restrict__ nbr,
    const unsigned short* __restrict__ W1p, const float* __restrict__ b1,
    const unsigned short* __restrict__ W2p, const float* __restrict__ b2,
    const float* __restrict__ gamma, const float* __restrict__ beta,
    const float* __restrict__ mean, const float* __restrict__ var,
    const float* __restrict__ eps_p,
    __hip_bfloat16* __restrict__ out_b,        // slice ptr, stride DD
    const int* __restrict__ batch, float* __restrict__ gsum, int soff,
    int N_) {
    __shared__ char s_agg[32 * 128];   // bf16 [32 nodes][64 k], XOR-swizzled
    __shared__ char s_h1[32 * 128];
    __shared__ char s_out[32 * 128];
    __shared__ int sb[32];

    const int t = threadIdx.x;
    const int lane = t & 63;
    const int w = t >> 6;
    const int node0 = blockIdx.x * 32;
    const int nb = w * 4;

    if (t < 32) sb[t] = (node0 + t < N_) ? batch[node0 + t] : -1;

    const float eps1 = 1.0f + eps_p[0];

    // ---- combined-span gather for this wave's 4 consecutive nodes ----
    const int n0w = node0 + nb;
    const int rp0 = __builtin_amdgcn_readfirstlane(rowptr[min(n0w + 0, N_)]);
    const int rp1 = __builtin_amdgcn_readfirstlane(rowptr[min(n0w + 1, N_)]);
    const int rp2 = __builtin_amdgcn_readfirstlane(rowptr[min(n0w + 2, N_)]);
    const int rp3 = __builtin_amdgcn_readfirstlane(rowptr[min(n0w + 3, N_)]);
    const int rp4 = __builtin_amdgcn_readfirstlane(rowptr[min(n0w + 4, N_)]);
    const int cnt = rp4 - rp0;
    const int e1 = rp1 - rp0, e2 = rp2 - rp0, e3 = rp3 - rp0;
    const int* nbp = nbr + rp0;

    const int RSB = (K == 64) ? DD * 2 : 64;       // gather row stride (bytes)
    const int OST = (K == 64) ? DD : 32;           // own-row stride (elems)
    const char* hbase = (const char*)hin_b;
    const unsigned lane2 = (unsigned)(lane & (K - 1)) * 2u;

    int idx[16];
    float vA[16], vB[16], vC[16];
    float run = 0.f, s0 = 0.f, s1 = 0.f, s2 = 0.f, s3 = 0.f;
    #pragma unroll
    for (int u = 0; u < 16; ++u) idx[u] = nbp[u];
    #pragma unroll
    for (int u = 0; u < 16; ++u)
        vA[u] = bf2f(*(const unsigned short*)(hbase + (unsigned)idx[u] * (unsigned)RSB + lane2));
    #pragma unroll
    for (int u = 0; u < 16; ++u) idx[u] = nbp[16 + u];
    #pragma unroll
    for (int u = 0; u < 16; ++u)
        vB[u] = bf2f(*(const unsigned short*)(hbase + (unsigned)idx[u] * (unsigned)RSB + lane2));
    #pragma unroll
    for (int u = 0; u < 16; ++u) idx[u] = nbp[32 + u];
    for (int k = 0;;) {
        GSTEP(vA, vC)
        GSTEP(vB, vA)
        GSTEP(vC, vB)
    }
    float a0 = s0, a1 = s1 - s0, a2 = s2 - s1, a3 = s3 - s2;
    {
        const unsigned short* hbp = hin_b + (lane & (K - 1));
        if (n0w + 0 < N_) a0 += eps1 * bf2f(hbp[(size_t)(n0w + 0) * OST]);
        if (n0w + 1 < N_) a1 += eps1 * bf2f(hbp[(size_t)(n0w + 1) * OST]);
        if (n0w + 2 < N_) a2 += eps1 * bf2f(hbp[(size_t)(n0w + 2) * OST]);
        if (n0w + 3 < N_) a3 += eps1 * bf2f(hbp[(size_t)(n0w + 3) * OST]);
    }
    if (K == 64 || lane < 32) {
        const int kd = lane & (K - 1);
        *(unsigned short*)(s_agg + SWZ(nb + 0, (nb + 0) * 128 + kd * 2)) = f2bf_u(a0);
        *(unsigned short*)(s_agg + SWZ(nb + 1, (nb + 1) * 128 + kd * 2)) = f2bf_u(a1);
        *(unsigned short*)(s_agg + SWZ(nb + 2, (nb + 2) * 128 + kd * 2)) = f2bf_u(a2);
        *(unsigned short*)(s_agg + SWZ(nb + 3, (nb + 3) * 128 + kd * 2)) = f2bf_u(a3);
    }
    __syncthreads();

    // ---- GEMM1: [32 x K] @ [K x 64] via MFMA; wave w -> C tile (mt, nt) ----
    const int mt = w >> 2, nt = w & 3;
    const int arow = mt * 16 + (lane & 15);
    const int col = nt * 16 + (lane & 15);
    f32x4 c1v = (f32x4){0.f, 0.f, 0.f, 0.f};
    #pragma unroll
    for (int ks = 0; ks < K / 32; ++ks) {
        bf16x8 a = *(const bf16x8*)(s_agg + SWZ(arow, arow * 128 + ks * 64 + ((lane >> 4) << 4)));
        bf16x8 b = *(const bf16x8*)(W1p + (((ks << 2) + nt) << 9) + (lane << 3));
        c1v = __builtin_amdgcn_mfma_f32_16x16x32_bf16(a, b, c1v, 0, 0, 0);
    }
    {
        const float bb1 = b1[col];
        #pragma unroll
        for (int reg = 0; reg < 4; ++reg) {
            int row = mt * 16 + ((lane >> 4) << 2) + reg;
            float v = fmaxf(c1v[reg] + bb1, 0.f);
            *(unsigned short*)(s_h1 + SWZ(row, row * 128 + col * 2)) = f2bf_u(v);
        }
    }
    __syncthreads();

    // ---- GEMM2: [32 x 64] @ [64 x 64] + BN epilogue ----
    f32x4 c2v = (f32x4){0.f, 0.f, 0.f, 0.f};
    #pragma unroll
    for (int ks = 0; ks < 2; ++ks) {
        bf16x8 a = *(const bf16x8*)(s_h1 + SWZ(arow, arow * 128 + ks * 64 + ((lane >> 4) << 4)));
        bf16x8 b = *(const bf16x8*)(W2p + (((ks << 2) + nt) << 9) + (lane << 3));
        c2v = __builtin_amdgcn_mfma_f32_16x16x32_bf16(a, b, c2v, 0, 0, 0);
    }
    {
        const float bb2 = b2[col];
        const float ga = gamma[col], bet = beta[col], mu = mean[col];
        const float iv = rsqrtf(var[col] + 1e-5f);
        #pragma unroll
        for (int reg = 0; reg < 4; ++reg) {
            int row = mt * 16 + ((lane >> 4) << 2) + reg;
            float v = fmaxf(c2v[reg] + bb2, 0.f);
            v = ga * (v - mu) * iv + bet;
            *(unsigned short*)(s_out + SWZ(row, row * 128 + col * 2)) = f2bf_u(v);
        }
    }
    __syncthreads();

    // ---- coalesced copy out: 32 rows x 128B, 16 threads/row x 8B ----
    {
        int r = t >> 4, c8 = t & 15;
        int node = node0 + r;
        if (node < N_) {
            ushort4 v = *(const ushort4*)(s_out + SWZ(r, r * 128 + c8 * 8));
            *(ushort4*)((unsigned short*)out_b + (size_t)node * DD + c8 * 4) = v;
        }
    }

    // ---- fused mean-pool accumulation for this slice (batch sorted) ----
    if (t < 256) {
        const int d = t & 63;
        const int rg = t >> 6;
        float acc = 0.f;
        int curg = sb[rg * 8];
        #pragma unroll
        for (int r = rg * 8; r < rg * 8 + 8; ++r) {
            int g = sb[r];
            if (g != curg) {
                if (curg >= 0) atomicAdd(&gsum[curg * DD + soff + d], acc);
                acc = 0.f; curg = g;
            }
            if (g >= 0)
                acc += bf2f(*(const unsigned short*)(s_out + SWZ(r, r * 128 + d * 2)));
        }
        if (curg >= 0) atomicAdd(&gsum[curg * DD + soff + d], acc);
    }
}

// ---------------------------------------------------------------------------
// Classification head: one block per graph (fp32 throughout).
// ---------------------------------------------------------------------------
__global__ void head_kernel(const float* __restrict__ gsum, const int* __restrict__ gcnt_i,
                            const float* __restrict__ W1, const float* __restrict__ b1,
                            const float* __restrict__ W2, const float* __restrict__ b2,
                            const float* __restrict__ W3, const float* __restrict__ b3,
                            const float* __restrict__ W4, const float* __restrict__ b4,
                            float* __restrict__ class_out, int* __restrict__ comp_idx) {
    const int g = blockIdx.x;
    const int t = threadIdx.x;
    __shared__ float ge[DD], h1[128], h2[64], h3[64], logits[NCC];

    const float c = fmaxf((float)gcnt_i[g], 1.0f);
    if (t < DD) ge[t] = gsum[g * DD + t] / c;
    __syncthreads();

    if (t < 128) {
        float a = b1[t];
        #pragma unroll 4
        for (int k = 0; k < DD; ++k) a += ge[k] * W1[k * 128 + t];
        h1[t] = fmaxf(a, 0.0f);
    }
    __syncthreads();
    if (t < 64) {
        float a = b2[t];
        #pragma unroll 4
        for (int k = 0; k < 128; ++k) a += h1[k] * W2[k * 64 + t];
        h2[t] = fmaxf(a, 0.0f);
    }
    __syncthreads();
    if (t < 64) {
        float a = b3[t];
        #pragma unroll 4
        for (int k = 0; k < 64; ++k) a += h2[k] * W3[k * 64 + t];
        h3[t] = fmaxf(a, 0.0f);
    }
    __syncthreads();
    if (t < NCC) {
        float a = b4[t];
        #pragma unroll
        for (int k = 0; k < 64; ++k) a += h3[k] * W4[k * NCC + t];
        logits[t] = a;
    }
    __syncthreads();
    if (t == 0) {
        float mx = logits[0]; int am = 0;
        for (int j = 1; j < NCC; ++j) if (logits[j] > mx) { mx = logits[j]; am = j; }
        float se = 0.0f;
        for (int j = 0; j < NCC; ++j) se += expf(logits[j] - mx);
        float lse = logf(se);
        for (int j = 0; j < NCC; ++j) class_out[g * NCC + j] = logits[j] - mx - lse;
        comp_idx[g] = am;
    }
}

// ---------------------------------------------------------------------------
// prep_edge: pack ep_W1 (rows 192..383) and ep_W2 into MFMA B-fragment order;
// pc[10][128] = comp_emb @ W1a + b1.
// ---------------------------------------------------------------------------
__global__ void prep_edge(const float* __restrict__ W1, const float* __restrict__ b1,
                          const float* __restrict__ W2, const float* __restrict__ comp_emb,
                          unsigned short* __restrict__ W1b_p, unsigned short* __restrict__ W2_p,
                          float* __restrict__ pc) {
    int idx = blockIdx.x * 256 + threadIdx.x;
    const int S1 = 6 * 8 * 512;
    const int S2 = 4 * 4 * 512;
    if (idx < S1) {
        int frag = idx >> 9;
        int lane = (idx >> 3) & 63;
        int j = idx & 7;
        int kstep = frag >> 3, nt = frag & 7;
        int k = kstep * 32 + ((lane >> 4) << 3) + j;
        int n = nt * 16 + (lane & 15);
        W1b_p[idx] = f2bf_u(W1[(192 + k) * 128 + n]);
    } else if (idx < S1 + S2) {
        int i2 = idx - S1;
        int frag = i2 >> 9;
        int lane = (i2 >> 3) & 63;
        int j = i2 & 7;
        int kstep = frag >> 2, nt = frag & 3;
        int k = kstep * 32 + ((lane >> 4) << 3) + j;
        int n = nt * 16 + (lane & 15);
        W2_p[i2] = f2bf_u(W2[k * 64 + n]);
    } else if (idx < S1 + S2 + NCC * 128) {
        int i3 = idx - (S1 + S2);
        int ci = i3 >> 7, col = i3 & 127;
        float a = b1[col];
        for (int k = 0; k < DD; ++k) a += comp_emb[ci * DD + k] * W1[k * 128 + col];
        pc[i3] = a;
    }
}

// ---------------------------------------------------------------------------
// edge_mfma (R10): 64 candidates / 256-thread block, col-split waves.
// ---------------------------------------------------------------------------
__global__ __launch_bounds__(256, 5) void edge_mfma(
    const int* __restrict__ cand, const int* __restrict__ batch,
    const int* __restrict__ comp_idx, const short* __restrict__ hb,
    const unsigned short* __restrict__ W1b_p, const unsigned short* __restrict__ W2_p,
    const float* __restrict__ pc, const float* __restrict__ W3,
    const float* __restrict__ b3, float* __restrict__ scores, int C_) {
    __shared__ char s_buf[64 * 384];   // de (24KB); h1 reuses first 16KB
    __shared__ float s_part[4][64];
    __shared__ int s_node[64];
    __shared__ int s_ci[64];
    __shared__ float s_w3[64];

    const int t = threadIdx.x;
    const int lane = t & 63;
    const int w = t >> 6;
    const int c0 = blockIdx.x * 64;

    if (t < 64) {
        int c = c0 + t;
        int node = (c < C_) ? cand[c] : cand[0];
        s_node[t] = node;
        s_ci[t] = comp_idx[batch[node]];
        s_w3[t] = W3[t];
    }
    __syncthreads();

    for (int i = t; i < 64 * 24; i += 256) {
        int r = i / 24, c8 = i - r * 24;
        bf16x8 v = *(const bf16x8*)(hb + (size_t)s_node[r] * DD + c8 * 8);
        *(bf16x8*)(s_buf + SWZ(r, r * 384 + c8 * 16)) = v;
    }
    __syncthreads();

    f32x4 acc1[4][2];
    #pragma unroll
    for (int rt = 0; rt < 4; ++rt)
        #pragma unroll
        for (int b = 0; b < 2; ++b) acc1[rt][b] = (f32x4){0.f, 0.f, 0.f, 0.f};
    #pragma unroll
    for (int ks = 0; ks < 6; ++ks) {
        bf16x8 b0 = *(const bf16x8*)(W1b_p + ((ks * 8 + 2 * w + 0) << 9) + (lane << 3));
        bf16x8 b1f = *(const bf16x8*)(W1b_p + ((ks * 8 + 2 * w + 1) << 9) + (lane << 3));
        #pragma unroll
        for (int rt = 0; rt < 4; ++rt) {
            int arow = rt * 16 + (lane & 15);
            bf16x8 a = *(const bf16x8*)(s_buf + SWZ(arow, arow * 384 + ks * 64 + ((lane >> 4) << 4)));
            acc1[rt][0] = __builtin_amdgcn_mfma_f32_16x16x32_bf16(a, b0, acc1[rt][0], 0, 0, 0);
            acc1[rt][1] = __builtin_amdgcn_mfma_f32_16x16x32_bf16(a, b1f, acc1[rt][1], 0, 0, 0);
        }
    }
    __syncthreads();

    #pragma unroll
    for (int rt = 0; rt < 4; ++rt) {
        #pragma unroll
        for (int reg = 0; reg < 4; ++reg) {
            int row = rt * 16 + ((lane >> 4) << 2) + reg;
            int ci = s_ci[row];
            #pragma unroll
            for (int b = 0; b < 2; ++b) {
                int col = (2 * w + b) * 16 + (lane & 15);
                float v = fmaxf(acc1[rt][b][reg] + pc[ci * 128 + col], 0.f);
                *(unsigned short*)(s_buf + SWZ(row, row * 256 + col * 2)) = f2bf_u(v);
            }
        }
    }
    __syncthreads();

    f32x4 acc2[4];
    #pragma unroll
    for (int rt = 0; rt < 4; ++rt) acc2[rt] = (f32x4){0.f, 0.f, 0.f, 0.f};
    #pragma unroll
    for (int ks = 0; ks < 4; ++ks) {
        bf16x8 b = *(const bf16x8*)(W2_p + ((ks * 4 + w) << 9) + (lane << 3));
        #pragma unroll
        for (int rt = 0; rt < 4; ++rt) {
            int arow = rt * 16 + (lane & 15);
            bf16x8 a = *(const bf16x8*)(s_buf + SWZ(arow, arow * 256 + ks * 64 + ((lane >> 4) << 4)));
            acc2[rt] = __builtin_amdgcn_mfma_f32_16x16x32_bf16(a, b, acc2[rt], 0, 0, 0);
        }
    }

    {
        const float w3v = s_w3[w * 16 + (lane & 15)];
        #pragma unroll
        for (int rt = 0; rt < 4; ++rt) {
            #pragma unroll
            for (int reg = 0; reg < 4; ++reg) {
                float p = fmaxf(acc2[rt][reg], 0.f) * w3v;
                p += __shfl_xor(p, 1);
                p += __shfl_xor(p, 2);
                p += __shfl_xor(p, 4);
                p += __shfl_xor(p, 8);
                if ((lane & 15) == 0)
                    s_part[w][rt * 16 + ((lane >> 4) << 2) + reg] = p;
            }
        }
    }
    __syncthreads();

    if (t < 64) {
        int c = c0 + t;
        if (c < C_) {
            float p = s_part[0][t] + s_part[1][t] + s_part[2][t] + s_part[3][t] + b3[0];
            scores[c] = 1.0f / (1.0f + expf(-p));
        }
    }
}

// ---------------------------------------------------------------------------
extern "C" void kernel_launch(void* const* d_in, const int* in_sizes, int n_in,
                              void* d_out, int out_size, void* d_ws, size_t ws_size,
                              hipStream_t stream) {
    const float* x        = (const float*)d_in[0];
    const int*   ei       = (const int*)d_in[1];
    const int*   batch    = (const int*)d_in[2];
    const int*   cand     = (const int*)d_in[3];
    const float* c1_W1    = (const float*)d_in[4];
    const float* c1_b1    = (const float*)d_in[5];
    const float* c1_W2    = (const float*)d_in[6];
    const float* c1_b2    = (const float*)d_in[7];
    const float* c1_g     = (const float*)d_in[8];
    const float* c1_be    = (const float*)d_in[9];
    const float* c1_m     = (const float*)d_in[10];
    const float* c1_v     = (const float*)d_in[11];
    const float* c1_eps   = (const float*)d_in[12];
    const float* cs_W1    = (const float*)d_in[13];
    const float* cs_b1    = (const float*)d_in[14];
    const float* cs_W2    = (const float*)d_in[15];
    const float* cs_b2    = (const float*)d_in[16];
    const float* cs_g     = (const float*)d_in[17];
    const float* cs_be    = (const float*)d_in[18];
    const float* cs_m     = (const float*)d_in[19];
    const float* cs_v     = (const float*)d_in[20];
    const float* cs_eps   = (const float*)d_in[21];
    const float* nc_W1    = (const float*)d_in[22];
    const float* nc_b1    = (const float*)d_in[23];
    const float* nc_W2    = (const float*)d_in[24];
    const float* nc_b2    = (const float*)d_in[25];
    const float* nc_W3    = (const float*)d_in[26];
    const float* nc_b3    = (const float*)d_in[27];
    const float* nc_W4    = (const float*)d_in[28];
    const float* nc_b4    = (const float*)d_in[29];
    const float* comp_emb = (const float*)d_in[30];
    const float* ep_W1    = (const float*)d_in[31];
    const float* ep_b1    = (const float*)d_in[32];
    const float* ep_W2    = (const float*)d_in[33];
    const float* ep_b2    = (const float*)d_in[34];
    const float* ep_W3    = (const float*)d_in[35];
    const float* ep_b3    = (const float*)d_in[36];

    const int N_ = in_sizes[0] / 32;
    const int E_ = in_sizes[1] / 2;
    const int C_ = in_sizes[3];
    const int* src = ei;
    const int* dst = ei + E_;
    const int NB = (N_ + (1 << BSH) - 1) >> BSH;   // 391 buckets of 256 nodes

    char* ws = (char*)d_ws;
    size_t off = 0;
    __hip_bfloat16* hb = (__hip_bfloat16*)(ws + off); off += (size_t)N_ * DD * 2;
    unsigned short* xb = (unsigned short*)(ws + off); off += (size_t)N_ * 32 * 2;
    int*   rowptr   = (int*)(ws + off);   off += (size_t)(N_ + 2) * 4;
    int*   nbr      = (int*)(ws + off);   off += (size_t)(E_ + 128) * 4;
    int*   bcnt     = (int*)(ws + off);   off += 2048;
    int*   bbase    = (int*)(ws + off);   off += 2080;   // NB+1 ints
    int*   bpos     = (int*)(ws + off);   off += 2048;
    float* gsum     = (float*)(ws + off); off += (size_t)GG * DD * 4;
    int*   gcnt_i   = (int*)(ws + off);   off += 1024;
    int*   comp_idx = (int*)(ws + off);   off += 1024;
    float* pc       = (float*)(ws + off); off += NCC * 128 * 4;
    unsigned short* W1b_p = (unsigned short*)(ws + off); off += 6 * 8 * 512 * 2;
    unsigned short* W2_p  = (unsigned short*)(ws + off); off += 4 * 4 * 512 * 2;
    unsigned short* enc   = (unsigned short*)(ws + off); off += 22528 * 2;
    // ebuf (E x 4B = 4.8MB) aliases hb: fully consumed by csr_bucket before
    // the first gin_fused writes hb (same stream, serial).
    unsigned* ebuf  = (unsigned*)hb;

    float* class_out = (float*)d_out;
    float* scores    = class_out + GG * NCC;

    // ---- weight prep + x->bf16 (independent of graph pipeline) ----
    prep_edge<<<(6 * 8 * 512 + 4 * 4 * 512 + NCC * 128 + 255) / 256, 256, 0, stream>>>(
        ep_W1, ep_b1, ep_W2, comp_emb, W1b_p, W2_p, pc);
    prep_enc<<<(22528 + 255) / 256, 256, 0, stream>>>(c1_W1, c1_W2, cs_W1, cs_W2, enc);
    x2b_kernel<<<2048, 256, 0, stream>>>(x, xb, N_ * 32);

    // ---- binned CSR build (packed 4B edges) ----
    hipMemsetAsync(bcnt, 0, 2048, stream);
    hipMemsetAsync(nbr + E_, 0, 128 * 4, stream);
    bin_hist<<<1024, 256, 0, stream>>>(dst, bcnt, E_);
    bin_scan<<<1, 256, 0, stream>>>(bcnt, bbase, bpos, NB, E_);
    bin_scatter<<<(E_ + 4095) / 4096, 256, 0, stream>>>(src, dst, bpos, ebuf, E_);
    csr_bucket<<<NB, 256, 0, stream>>>(ebuf, bbase, rowptr, nbr, N_, NB);

    // ---- pool accumulators ----
    hipMemsetAsync(gsum, 0, (size_t)GG * DD * 4, stream);
    gcnt_bs<<<1, GG, 0, stream>>>(batch, gcnt_i, N_);

    // ---- GIN layers (fused gather + MFMA MLP + fused pool) ----
    const int gblk = (N_ + 31) / 32;
    gin_fused<32><<<gblk, 512, 0, stream>>>(
        xb, rowptr, nbr,
        enc + 0, c1_b1, enc + 2048, c1_b2,
        c1_g, c1_be, c1_m, c1_v, c1_eps, hb + 0, batch, gsum, 0, N_);
    gin_fused<64><<<gblk, 512, 0, stream>>>(
        (const unsigned short*)hb + 0, rowptr, nbr,
        enc + 6144, cs_b1 + 0, enc + 10240, cs_b2 + 0,
        cs_g + 0, cs_be + 0, cs_m + 0, cs_v + 0, cs_eps + 0, hb + 64, batch, gsum, 64, N_);
    gin_fused<64><<<gblk, 512, 0, stream>>>(
        (const unsigned short*)hb + 64, rowptr, nbr,
        enc + 14336, cs_b1 + 64, enc + 18432, cs_b2 + 64,
        cs_g + 64, cs_be + 64, cs_m + 64, cs_v + 64, cs_eps + 1, hb + 128, batch, gsum, 128, N_);

    // ---- head ----
    head_kernel<<<GG, 256, 0, stream>>>(gsum, gcnt_i, nc_W1, nc_b1, nc_W2, nc_b2,
                                        nc_W3, nc_b3, nc_W4, nc_b4, class_out, comp_idx);

    // ---- edge prediction (MFMA) ----
    edge_mfma<<<(C_ + 63) / 64, 256, 0, stream>>>(
        cand, batch, comp_idx, (const short*)hb, W1b_p, W2_p, pc, ep_W3, ep_b3, scores, C_);
}

// Round 14
// 286.753 us; speedup vs baseline: 1.0867x; 1.0867x over previous
//
#include <hip/hip_runtime.h>
#include <hip/hip_bf16.h>

// Problem constants (MultiTaskFEGIN): N=100000, E=1200000, F=32, H=64, L=3,
// G=256, C=200000, NC=10, D=L*H=192.

#define GG 256
#define NCC 10
#define DD 192
#define BSH 8          // bucket shift: 256 nodes/bucket (NB <= 512 for N <= 131072)

typedef short bf16x8 __attribute__((ext_vector_type(8)));
typedef float f32x4  __attribute__((ext_vector_type(4)));

__device__ inline unsigned short f2bf_u(float x) {
    __hip_bfloat16 h = __float2bfloat16(x);
    return *reinterpret_cast<unsigned short*>(&h);
}
__device__ inline float bf2f(unsigned short u) {
    return __uint_as_float(((unsigned int)u) << 16);
}

// ---------------------------------------------------------------------------
// Binned CSR build: packed (src<<BSH)|dst_local ints (half the scatter bytes);
// contiguous per-bucket regions -> full-line fills.
// ---------------------------------------------------------------------------
__global__ void bin_hist(const int* __restrict__ dst, int* __restrict__ bcnt, int E_) {
    __shared__ int h[512];
    const int t = threadIdx.x;
    h[t] = 0; h[t + 256] = 0;
    __syncthreads();
    for (int e = blockIdx.x * 256 + t; e < E_; e += gridDim.x * 256)
        atomicAdd(&h[dst[e] >> BSH], 1);
    __syncthreads();
    if (h[t]) atomicAdd(&bcnt[t], h[t]);
    if (h[t + 256]) atomicAdd(&bcnt[t + 256], h[t + 256]);
}

__global__ void bin_scan(const int* __restrict__ bcnt, int* __restrict__ bbase,
                         int* __restrict__ bpos, int NB, int E_) {
    __shared__ int ps[256];
    const int t = threadIdx.x;
    int v0 = (2 * t < NB) ? bcnt[2 * t] : 0;
    int v1 = (2 * t + 1 < NB) ? bcnt[2 * t + 1] : 0;
    int pv = v0 + v1;
    ps[t] = pv;
    __syncthreads();
    for (int off = 1; off < 256; off <<= 1) {
        int x = (t >= off) ? ps[t - off] : 0;
        __syncthreads();
        ps[t] += x;
        __syncthreads();
    }
    const int excl = ps[t] - pv;
    if (2 * t < NB)     { bbase[2 * t] = excl;          bpos[2 * t] = excl; }
    if (2 * t + 1 < NB) { bbase[2 * t + 1] = excl + v0; bpos[2 * t + 1] = excl + v0; }
    if (t == 0) bbase[NB] = E_;
}

// 4096 edges/block (16/thread): rank in LDS, one range-claim per bucket,
// packed 4B scatter writes in contiguous runs.
__global__ __launch_bounds__(256) void bin_scatter(
    const int* __restrict__ src, const int* __restrict__ dst,
    int* __restrict__ bpos, unsigned* __restrict__ ebuf, int E_) {
    __shared__ int h[512];
    __shared__ int base[512];
    const int t = threadIdx.x;
    const int e0 = blockIdx.x * 4096;
    h[t] = 0; h[t + 256] = 0;
    __syncthreads();
    int myb[16], myr[16];
    unsigned pk[16];
    #pragma unroll
    for (int u = 0; u < 16; ++u) {
        int e = e0 + t + u * 256;
        if (e < E_) {
            int d = dst[e];
            myb[u] = d >> BSH;
            pk[u] = ((unsigned)src[e] << BSH) | (unsigned)(d & ((1 << BSH) - 1));
            myr[u] = atomicAdd(&h[myb[u]], 1);
        } else myb[u] = -1;
    }
    __syncthreads();
    if (h[t]) base[t] = atomicAdd(&bpos[t], h[t]);
    if (h[t + 256]) base[t + 256] = atomicAdd(&bpos[t + 256], h[t + 256]);
    __syncthreads();
    #pragma unroll
    for (int u = 0; u < 16; ++u)
        if (myb[u] >= 0)
            ebuf[base[myb[u]] + myr[u]] = pk[u];
}

// One block per 256-node bucket: local histogram -> scan -> rowptr -> nbr.
__global__ __launch_bounds__(256) void csr_bucket(
    const unsigned* __restrict__ ebuf, const int* __restrict__ bbase,
    int* __restrict__ rowptr, int* __restrict__ nbr, int N_, int NB) {
    __shared__ int lh[256];
    __shared__ int lx[256];
    __shared__ int ps[256];
    const int b = blockIdx.x;
    const int t = threadIdx.x;
    const int ebase = bbase[b], eend = bbase[b + 1];
    const int ecnt = eend - ebase;
    const int n0 = b << BSH;

    lh[t] = 0;
    __syncthreads();
    for (int i = t; i < ecnt; i += 256)
        atomicAdd(&lh[ebuf[ebase + i] & ((1 << BSH) - 1)], 1);
    __syncthreads();

    int v = lh[t];
    ps[t] = v;
    __syncthreads();
    for (int off = 1; off < 256; off <<= 1) {
        int x = (t >= off) ? ps[t - off] : 0;
        __syncthreads();
        ps[t] += x;
        __syncthreads();
    }
    lx[t] = ps[t] - v;
    {
        int n = n0 + t;
        if (n < N_) rowptr[n] = ebase + lx[t];
    }
    if (b == NB - 1 && t == 0) rowptr[N_] = eend;
    __syncthreads();
    lh[t] = lx[t];
    __syncthreads();
    for (int i = t; i < ecnt; i += 256) {
        unsigned p = ebuf[ebase + i];
        int r = atomicAdd(&lh[p & ((1 << BSH) - 1)], 1);
        nbr[ebase + r] = (int)(p >> BSH);
    }
}

// ---------------------------------------------------------------------------
// x2b: x [N][32] fp32 -> bf16 (64B gather rows, slice L2-friendly).
// ---------------------------------------------------------------------------
__global__ void x2b_kernel(const float* __restrict__ x, unsigned short* __restrict__ xb,
                           int n_elem) {
    int i = blockIdx.x * 256 + threadIdx.x;
    int stride = gridDim.x * 256;
    for (; i * 4 < n_elem; i += stride) {
        float4 v = *(const float4*)(x + i * 4);
        ushort4 u;
        u.x = f2bf_u(v.x); u.y = f2bf_u(v.y); u.z = f2bf_u(v.z); u.w = f2bf_u(v.w);
        *(ushort4*)(xb + i * 4) = u;
    }
}

// ---------------------------------------------------------------------------
// prep_enc: pack the 6 encoder weight matrices into MFMA B-fragment bf16.
// ---------------------------------------------------------------------------
__global__ void prep_enc(const float* __restrict__ c1W1, const float* __restrict__ c1W2,
                         const float* __restrict__ csW1, const float* __restrict__ csW2,
                         unsigned short* __restrict__ enc) {
    int idx = blockIdx.x * 256 + threadIdx.x;
    if (idx >= 22528) return;
    const float* W; int rel;
    if (idx < 2048)       { W = c1W1;        rel = idx; }
    else if (idx < 6144)  { W = c1W2;        rel = idx - 2048; }
    else if (idx < 10240) { W = csW1;        rel = idx - 6144; }
    else if (idx < 14336) { W = csW2;        rel = idx - 10240; }
    else if (idx < 18432) { W = csW1 + 4096; rel = idx - 14336; }
    else                  { W = csW2 + 4096; rel = idx - 18432; }
    int frag = rel >> 9;
    int lane = (rel >> 3) & 63;
    int j = rel & 7;
    int ks = frag >> 2, nt = frag & 3;
    int k = ks * 32 + ((lane >> 4) << 3) + j;
    int n = nt * 16 + (lane & 15);
    enc[idx] = f2bf_u(W[k * 64 + n]);
}

// ---------------------------------------------------------------------------
// gcnt by binary search (batch sorted).
// ---------------------------------------------------------------------------
__global__ void gcnt_bs(const int* __restrict__ batch, int* __restrict__ gcnt_i, int N_) {
    __shared__ int lbs[GG + 1];
    const int g = threadIdx.x;
    int lo = 0, hi = N_;
    while (lo < hi) {
        int mid = (lo + hi) >> 1;
        if (batch[mid] < g) lo = mid + 1; else hi = mid;
    }
    lbs[g] = lo;
    if (g == 0) lbs[GG] = N_;
    __syncthreads();
    gcnt_i[g] = lbs[g + 1] - lbs[g];
}

// ---------------------------------------------------------------------------
// Fused GIN layer: 2-deep pipelined running-sum gather (R12-proven depth:
// VGPR ~40 keeps occupancy ~47%) -> MFMA MLP -> BN -> hb slice + fused pool.
// Unified K=32/64: all lanes read element lane&(K-1) of each row (K=32 upper
// half redundant, same cache line; s_agg writes guarded). Boundaries via
// per-chunk uniform-branch prefix fixups. nbr padded >=64 zeroed ints past E.
// ---------------------------------------------------------------------------
#define SWZ(row, byte) ((byte) ^ (((row) & 7) << 4))

#define GSTEP(VCUR, VNXT)                                                     \
    _Pragma("unroll")                                                         \
    for (int u = 0; u < 16; ++u)                                              \
        VNXT[u] = bf2f(*(const unsigned short*)(hbase + (unsigned)idx[u] * (unsigned)RSB + lane2)); \
    _Pragma("unroll")                                                         \
    for (int u = 0; u < 16; ++u) idx[u] = nbp[k + 32 + u];                    \
    {                                                                         \
        float runk = run;                                                     \
        _Pragma("unroll")                                                     \
        for (int u = 0; u < 16; ++u) run += VCUR[u];                          \
        if ((unsigned)(e1 - k) < 16u) { float tt = runk;                      \
            _Pragma("unroll")                                                 \
            for (int u = 0; u < 16; ++u) tt += (u < e1 - k) ? VCUR[u] : 0.f;  \
            s0 = tt; }                                                        \
        if ((unsigned)(e2 - k) < 16u) { float tt = runk;                      \
            _Pragma("unroll")                                                 \
            for (int u = 0; u < 16; ++u) tt += (u < e2 - k) ? VCUR[u] : 0.f;  \
            s1 = tt; }                                                        \
        if ((unsigned)(e3 - k) < 16u) { float tt = runk;                      \
            _Pragma("unroll")                                                 \
            for (int u = 0; u < 16; ++u) tt += (u < e3 - k) ? VCUR[u] : 0.f;  \
            s2 = tt; }                                                        \
        if ((unsigned)(cnt - k) < 16u) { float tt = runk;                     \
            _Pragma("unroll")                                                 \
            for (int u = 0; u < 16; ++u) tt += (u < cnt - k) ? VCUR[u] : 0.f; \
            s3 = tt; }                                                        \
    }                                                                         \
    k += 16;                                                                  \
    if (k > cnt) break;

template<int K>
__global__ __launch_bounds__(512) void gin_fused(
    const unsigned short* __restrict__ hin_b,  // bf16 rows: stride DD (K=64) / 32 (K=32)
    const int* __restrict__ rowptr, const int* __restrict__ nbr,
    const unsigned short* __restrict__ W1p, const float* __restrict__ b1,
    const unsigned short* __restrict__ W2p, const float* __restrict__ b2,
    const float* __restrict__ gamma, const float* __restrict__ beta,
    const float* __restrict__ mean, const float* __restrict__ var,
    const float* __restrict__ eps_p,
    __hip_bfloat16* __restrict__ out_b,        // slice ptr, stride DD
    const int* __restrict__ batch, float* __restrict__ gsum, int soff,
    int N_) {
    __shared__ char s_agg[32 * 128];   // bf16 [32 nodes][64 k], XOR-swizzled
    __shared__ char s_h1[32 * 128];
    __shared__ char s_out[32 * 128];
    __shared__ int sb[32];

    const int t = threadIdx.x;
    const int lane = t & 63;
    const int w = t >> 6;
    const int node0 = blockIdx.x * 32;
    const int nb = w * 4;

    if (t < 32) sb[t] = (node0 + t < N_) ? batch[node0 + t] : -1;

    const float eps1 = 1.0f + eps_p[0];

    // ---- combined-span gather for this wave's 4 consecutive nodes ----
    const int n0w = node0 + nb;
    const int rp0 = __builtin_amdgcn_readfirstlane(rowptr[min(n0w + 0, N_)]);
    const int rp1 = __builtin_amdgcn_readfirstlane(rowptr[min(n0w + 1, N_)]);
    const int rp2 = __builtin_amdgcn_readfirstlane(rowptr[min(n0w + 2, N_)]);
    const int rp3 = __builtin_amdgcn_readfirstlane(rowptr[min(n0w + 3, N_)]);
    const int rp4 = __builtin_amdgcn_readfirstlane(rowptr[min(n0w + 4, N_)]);
    const int cnt = rp4 - rp0;
    const int e1 = rp1 - rp0, e2 = rp2 - rp0, e3 = rp3 - rp0;
    const int* nbp = nbr + rp0;

    const int RSB = (K == 64) ? DD * 2 : 64;       // gather row stride (bytes)
    const int OST = (K == 64) ? DD : 32;           // own-row stride (elems)
    const char* hbase = (const char*)hin_b;
    const unsigned lane2 = (unsigned)(lane & (K - 1)) * 2u;

    int idx[16];
    float vA[16], vB[16];
    float run = 0.f, s0 = 0.f, s1 = 0.f, s2 = 0.f, s3 = 0.f;
    #pragma unroll
    for (int u = 0; u < 16; ++u) idx[u] = nbp[u];
    #pragma unroll
    for (int u = 0; u < 16; ++u)
        vA[u] = bf2f(*(const unsigned short*)(hbase + (unsigned)idx[u] * (unsigned)RSB + lane2));
    #pragma unroll
    for (int u = 0; u < 16; ++u) idx[u] = nbp[16 + u];
    for (int k = 0;;) {
        GSTEP(vA, vB)
        GSTEP(vB, vA)
    }
    float a0 = s0, a1 = s1 - s0, a2 = s2 - s1, a3 = s3 - s2;
    {
        const unsigned short* hbp = hin_b + (lane & (K - 1));
        if (n0w + 0 < N_) a0 += eps1 * bf2f(hbp[(size_t)(n0w + 0) * OST]);
        if (n0w + 1 < N_) a1 += eps1 * bf2f(hbp[(size_t)(n0w + 1) * OST]);
        if (n0w + 2 < N_) a2 += eps1 * bf2f(hbp[(size_t)(n0w + 2) * OST]);
        if (n0w + 3 < N_) a3 += eps1 * bf2f(hbp[(size_t)(n0w + 3) * OST]);
    }
    if (K == 64 || lane < 32) {
        const int kd = lane & (K - 1);
        *(unsigned short*)(s_agg + SWZ(nb + 0, (nb + 0) * 128 + kd * 2)) = f2bf_u(a0);
        *(unsigned short*)(s_agg + SWZ(nb + 1, (nb + 1) * 128 + kd * 2)) = f2bf_u(a1);
        *(unsigned short*)(s_agg + SWZ(nb + 2, (nb + 2) * 128 + kd * 2)) = f2bf_u(a2);
        *(unsigned short*)(s_agg + SWZ(nb + 3, (nb + 3) * 128 + kd * 2)) = f2bf_u(a3);
    }
    __syncthreads();

    // ---- GEMM1: [32 x K] @ [K x 64] via MFMA; wave w -> C tile (mt, nt) ----
    const int mt = w >> 2, nt = w & 3;
    const int arow = mt * 16 + (lane & 15);
    const int col = nt * 16 + (lane & 15);
    f32x4 c1v = (f32x4){0.f, 0.f, 0.f, 0.f};
    #pragma unroll
    for (int ks = 0; ks < K / 32; ++ks) {
        bf16x8 a = *(const bf16x8*)(s_agg + SWZ(arow, arow * 128 + ks * 64 + ((lane >> 4) << 4)));
        bf16x8 b = *(const bf16x8*)(W1p + (((ks << 2) + nt) << 9) + (lane << 3));
        c1v = __builtin_amdgcn_mfma_f32_16x16x32_bf16(a, b, c1v, 0, 0, 0);
    }
    {
        const float bb1 = b1[col];
        #pragma unroll
        for (int reg = 0; reg < 4; ++reg) {
            int row = mt * 16 + ((lane >> 4) << 2) + reg;
            float v = fmaxf(c1v[reg] + bb1, 0.f);
            *(unsigned short*)(s_h1 + SWZ(row, row * 128 + col * 2)) = f2bf_u(v);
        }
    }
    __syncthreads();

    // ---- GEMM2: [32 x 64] @ [64 x 64] + BN epilogue ----
    f32x4 c2v = (f32x4){0.f, 0.f, 0.f, 0.f};
    #pragma unroll
    for (int ks = 0; ks < 2; ++ks) {
        bf16x8 a = *(const bf16x8*)(s_h1 + SWZ(arow, arow * 128 + ks * 64 + ((lane >> 4) << 4)));
        bf16x8 b = *(const bf16x8*)(W2p + (((ks << 2) + nt) << 9) + (lane << 3));
        c2v = __builtin_amdgcn_mfma_f32_16x16x32_bf16(a, b, c2v, 0, 0, 0);
    }
    {
        const float bb2 = b2[col];
        const float ga = gamma[col], bet = beta[col], mu = mean[col];
        const float iv = rsqrtf(var[col] + 1e-5f);
        #pragma unroll
        for (int reg = 0; reg < 4; ++reg) {
            int row = mt * 16 + ((lane >> 4) << 2) + reg;
            float v = fmaxf(c2v[reg] + bb2, 0.f);
            v = ga * (v - mu) * iv + bet;
            *(unsigned short*)(s_out + SWZ(row, row * 128 + col * 2)) = f2bf_u(v);
        }
    }
    __syncthreads();

    // ---- coalesced copy out: 32 rows x 128B, 16 threads/row x 8B ----
    {
        int r = t >> 4, c8 = t & 15;
        int node = node0 + r;
        if (node < N_) {
            ushort4 v = *(const ushort4*)(s_out + SWZ(r, r * 128 + c8 * 8));
            *(ushort4*)((unsigned short*)out_b + (size_t)node * DD + c8 * 4) = v;
        }
    }

    // ---- fused mean-pool accumulation for this slice (batch sorted) ----
    if (t < 256) {
        const int d = t & 63;
        const int rg = t >> 6;
        float acc = 0.f;
        int curg = sb[rg * 8];
        #pragma unroll
        for (int r = rg * 8; r < rg * 8 + 8; ++r) {
            int g = sb[r];
            if (g != curg) {
                if (curg >= 0) atomicAdd(&gsum[curg * DD + soff + d], acc);
                acc = 0.f; curg = g;
            }
            if (g >= 0)
                acc += bf2f(*(const unsigned short*)(s_out + SWZ(r, r * 128 + d * 2)));
        }
        if (curg >= 0) atomicAdd(&gsum[curg * DD + soff + d], acc);
    }
}

// ---------------------------------------------------------------------------
// Classification head: one block per graph (fp32 throughout).
// ---------------------------------------------------------------------------
__global__ void head_kernel(const float* __restrict__ gsum, const int* __restrict__ gcnt_i,
                            const float* __restrict__ W1, const float* __restrict__ b1,
                            const float* __restrict__ W2, const float* __restrict__ b2,
                            const float* __restrict__ W3, const float* __restrict__ b3,
                            const float* __restrict__ W4, const float* __restrict__ b4,
                            float* __restrict__ class_out, int* __restrict__ comp_idx) {
    const int g = blockIdx.x;
    const int t = threadIdx.x;
    __shared__ float ge[DD], h1[128], h2[64], h3[64], logits[NCC];

    const float c = fmaxf((float)gcnt_i[g], 1.0f);
    if (t < DD) ge[t] = gsum[g * DD + t] / c;
    __syncthreads();

    if (t < 128) {
        float a = b1[t];
        #pragma unroll 4
        for (int k = 0; k < DD; ++k) a += ge[k] * W1[k * 128 + t];
        h1[t] = fmaxf(a, 0.0f);
    }
    __syncthreads();
    if (t < 64) {
        float a = b2[t];
        #pragma unroll 4
        for (int k = 0; k < 128; ++k) a += h1[k] * W2[k * 64 + t];
        h2[t] = fmaxf(a, 0.0f);
    }
    __syncthreads();
    if (t < 64) {
        float a = b3[t];
        #pragma unroll 4
        for (int k = 0; k < 64; ++k) a += h2[k] * W3[k * 64 + t];
        h3[t] = fmaxf(a, 0.0f);
    }
    __syncthreads();
    if (t < NCC) {
        float a = b4[t];
        #pragma unroll
        for (int k = 0; k < 64; ++k) a += h3[k] * W4[k * NCC + t];
        logits[t] = a;
    }
    __syncthreads();
    if (t == 0) {
        float mx = logits[0]; int am = 0;
        for (int j = 1; j < NCC; ++j) if (logits[j] > mx) { mx = logits[j]; am = j; }
        float se = 0.0f;
        for (int j = 0; j < NCC; ++j) se += expf(logits[j] - mx);
        float lse = logf(se);
        for (int j = 0; j < NCC; ++j) class_out[g * NCC + j] = logits[j] - mx - lse;
        comp_idx[g] = am;
    }
}

// ---------------------------------------------------------------------------
// prep_edge: pack ep_W1 (rows 192..383) and ep_W2 into MFMA B-fragment order;
// pc[10][128] = comp_emb @ W1a + b1.
// ---------------------------------------------------------------------------
__global__ void prep_edge(const float* __restrict__ W1, const float* __restrict__ b1,
                          const float* __restrict__ W2, const float* __restrict__ comp_emb,
                          unsigned short* __restrict__ W1b_p, unsigned short* __restrict__ W2_p,
                          float* __restrict__ pc) {
    int idx = blockIdx.x * 256 + threadIdx.x;
    const int S1 = 6 * 8 * 512;
    const int S2 = 4 * 4 * 512;
    if (idx < S1) {
        int frag = idx >> 9;
        int lane = (idx >> 3) & 63;
        int j = idx & 7;
        int kstep = frag >> 3, nt = frag & 7;
        int k = kstep * 32 + ((lane >> 4) << 3) + j;
        int n = nt * 16 + (lane & 15);
        W1b_p[idx] = f2bf_u(W1[(192 + k) * 128 + n]);
    } else if (idx < S1 + S2) {
        int i2 = idx - S1;
        int frag = i2 >> 9;
        int lane = (i2 >> 3) & 63;
        int j = i2 & 7;
        int kstep = frag >> 2, nt = frag & 3;
        int k = kstep * 32 + ((lane >> 4) << 3) + j;
        int n = nt * 16 + (lane & 15);
        W2_p[i2] = f2bf_u(W2[k * 64 + n]);
    } else if (idx < S1 + S2 + NCC * 128) {
        int i3 = idx - (S1 + S2);
        int ci = i3 >> 7, col = i3 & 127;
        float a = b1[col];
        for (int k = 0; k < DD; ++k) a += comp_emb[ci * DD + k] * W1[k * 128 + col];
        pc[i3] = a;
    }
}

// ---------------------------------------------------------------------------
// edge_mfma (R10): 64 candidates / 256-thread block, col-split waves.
// ---------------------------------------------------------------------------
__global__ __launch_bounds__(256, 5) void edge_mfma(
    const int* __restrict__ cand, const int* __restrict__ batch,
    const int* __restrict__ comp_idx, const short* __restrict__ hb,
    const unsigned short* __restrict__ W1b_p, const unsigned short* __restrict__ W2_p,
    const float* __restrict__ pc, const float* __restrict__ W3,
    const float* __restrict__ b3, float* __restrict__ scores, int C_) {
    __shared__ char s_buf[64 * 384];   // de (24KB); h1 reuses first 16KB
    __shared__ float s_part[4][64];
    __shared__ int s_node[64];
    __shared__ int s_ci[64];
    __shared__ float s_w3[64];

    const int t = threadIdx.x;
    const int lane = t & 63;
    const int w = t >> 6;
    const int c0 = blockIdx.x * 64;

    if (t < 64) {
        int c = c0 + t;
        int node = (c < C_) ? cand[c] : cand[0];
        s_node[t] = node;
        s_ci[t] = comp_idx[batch[node]];
        s_w3[t] = W3[t];
    }
    __syncthreads();

    for (int i = t; i < 64 * 24; i += 256) {
        int r = i / 24, c8 = i - r * 24;
        bf16x8 v = *(const bf16x8*)(hb + (size_t)s_node[r] * DD + c8 * 8);
        *(bf16x8*)(s_buf + SWZ(r, r * 384 + c8 * 16)) = v;
    }
    __syncthreads();

    f32x4 acc1[4][2];
    #pragma unroll
    for (int rt = 0; rt < 4; ++rt)
        #pragma unroll
        for (int b = 0; b < 2; ++b) acc1[rt][b] = (f32x4){0.f, 0.f, 0.f, 0.f};
    #pragma unroll
    for (int ks = 0; ks < 6; ++ks) {
        bf16x8 b0 = *(const bf16x8*)(W1b_p + ((ks * 8 + 2 * w + 0) << 9) + (lane << 3));
        bf16x8 b1f = *(const bf16x8*)(W1b_p + ((ks * 8 + 2 * w + 1) << 9) + (lane << 3));
        #pragma unroll
        for (int rt = 0; rt < 4; ++rt) {
            int arow = rt * 16 + (lane & 15);
            bf16x8 a = *(const bf16x8*)(s_buf + SWZ(arow, arow * 384 + ks * 64 + ((lane >> 4) << 4)));
            acc1[rt][0] = __builtin_amdgcn_mfma_f32_16x16x32_bf16(a, b0, acc1[rt][0], 0, 0, 0);
            acc1[rt][1] = __builtin_amdgcn_mfma_f32_16x16x32_bf16(a, b1f, acc1[rt][1], 0, 0, 0);
        }
    }
    __syncthreads();

    #pragma unroll
    for (int rt = 0; rt < 4; ++rt) {
        #pragma unroll
        for (int reg = 0; reg < 4; ++reg) {
            int row = rt * 16 + ((lane >> 4) << 2) + reg;
            int ci = s_ci[row];
            #pragma unroll
            for (int b = 0; b < 2; ++b) {
                int col = (2 * w + b) * 16 + (lane & 15);
                float v = fmaxf(acc1[rt][b][reg] + pc[ci * 128 + col], 0.f);
                *(unsigned short*)(s_buf + SWZ(row, row * 256 + col * 2)) = f2bf_u(v);
            }
        }
    }
    __syncthreads();

    f32x4 acc2[4];
    #pragma unroll
    for (int rt = 0; rt < 4; ++rt) acc2[rt] = (f32x4){0.f, 0.f, 0.f, 0.f};
    #pragma unroll
    for (int ks = 0; ks < 4; ++ks) {
        bf16x8 b = *(const bf16x8*)(W2_p + ((ks * 4 + w) << 9) + (lane << 3));
        #pragma unroll
        for (int rt = 0; rt < 4; ++rt) {
            int arow = rt * 16 + (lane & 15);
            bf16x8 a = *(const bf16x8*)(s_buf + SWZ(arow, arow * 256 + ks * 64 + ((lane >> 4) << 4)));
            acc2[rt] = __builtin_amdgcn_mfma_f32_16x16x32_bf16(a, b, acc2[rt], 0, 0, 0);
        }
    }

    {
        const float w3v = s_w3[w * 16 + (lane & 15)];
        #pragma unroll
        for (int rt = 0; rt < 4; ++rt) {
            #pragma unroll
            for (int reg = 0; reg < 4; ++reg) {
                float p = fmaxf(acc2[rt][reg], 0.f) * w3v;
                p += __shfl_xor(p, 1);
                p += __shfl_xor(p, 2);
                p += __shfl_xor(p, 4);
                p += __shfl_xor(p, 8);
                if ((lane & 15) == 0)
                    s_part[w][rt * 16 + ((lane >> 4) << 2) + reg] = p;
            }
        }
    }
    __syncthreads();

    if (t < 64) {
        int c = c0 + t;
        if (c < C_) {
            float p = s_part[0][t] + s_part[1][t] + s_part[2][t] + s_part[3][t] + b3[0];
            scores[c] = 1.0f / (1.0f + expf(-p));
        }
    }
}

// ---------------------------------------------------------------------------
extern "C" void kernel_launch(void* const* d_in, const int* in_sizes, int n_in,
                              void* d_out, int out_size, void* d_ws, size_t ws_size,
                              hipStream_t stream) {
    const float* x        = (const float*)d_in[0];
    const int*   ei       = (const int*)d_in[1];
    const int*   batch    = (const int*)d_in[2];
    const int*   cand     = (const int*)d_in[3];
    const float* c1_W1    = (const float*)d_in[4];
    const float* c1_b1    = (const float*)d_in[5];
    const float* c1_W2    = (const float*)d_in[6];
    const float* c1_b2    = (const float*)d_in[7];
    const float* c1_g     = (const float*)d_in[8];
    const float* c1_be    = (const float*)d_in[9];
    const float* c1_m     = (const float*)d_in[10];
    const float* c1_v     = (const float*)d_in[11];
    const float* c1_eps   = (const float*)d_in[12];
    const float* cs_W1    = (const float*)d_in[13];
    const float* cs_b1    = (const float*)d_in[14];
    const float* cs_W2    = (const float*)d_in[15];
    const float* cs_b2    = (const float*)d_in[16];
    const float* cs_g     = (const float*)d_in[17];
    const float* cs_be    = (const float*)d_in[18];
    const float* cs_m     = (const float*)d_in[19];
    const float* cs_v     = (const float*)d_in[20];
    const float* cs_eps   = (const float*)d_in[21];
    const float* nc_W1    = (const float*)d_in[22];
    const float* nc_b1    = (const float*)d_in[23];
    const float* nc_W2    = (const float*)d_in[24];
    const float* nc_b2    = (const float*)d_in[25];
    const float* nc_W3    = (const float*)d_in[26];
    const float* nc_b3    = (const float*)d_in[27];
    const float* nc_W4    = (const float*)d_in[28];
    const float* nc_b4    = (const float*)d_in[29];
    const float* comp_emb = (const float*)d_in[30];
    const float* ep_W1    = (const float*)d_in[31];
    const float* ep_b1    = (const float*)d_in[32];
    const float* ep_W2    = (const float*)d_in[33];
    const float* ep_b2    = (const float*)d_in[34];
    const float* ep_W3    = (const float*)d_in[35];
    const float* ep_b3    = (const float*)d_in[36];

    const int N_ = in_sizes[0] / 32;
    const int E_ = in_sizes[1] / 2;
    const int C_ = in_sizes[3];
    const int* src = ei;
    const int* dst = ei + E_;
    const int NB = (N_ + (1 << BSH) - 1) >> BSH;

    char* ws = (char*)d_ws;
    size_t off = 0;
    __hip_bfloat16* hb = (__hip_bfloat16*)(ws + off); off += (size_t)N_ * DD * 2;
    unsigned short* xb = (unsigned short*)(ws + off); off += (size_t)N_ * 32 * 2;
    int*   rowptr   = (int*)(ws + off);   off += (size_t)(N_ + 2) * 4;
    int*   nbr      = (int*)(ws + off);   off += (size_t)(E_ + 128) * 4;
    int*   bcnt     = (int*)(ws + off);   off += 2048;
    int*   bbase    = (int*)(ws + off);   off += 2080;
    int*   bpos     = (int*)(ws + off);   off += 2048;
    float* gsum     = (float*)(ws + off); off += (size_t)GG * DD * 4;
    int*   gcnt_i   = (int*)(ws + off);   off += 1024;
    int*   comp_idx = (int*)(ws + off);   off += 1024;
    float* pc       = (float*)(ws + off); off += NCC * 128 * 4;
    unsigned short* W1b_p = (unsigned short*)(ws + off); off += 6 * 8 * 512 * 2;
    unsigned short* W2_p  = (unsigned short*)(ws + off); off += 4 * 4 * 512 * 2;
    unsigned short* enc   = (unsigned short*)(ws + off); off += 22528 * 2;
    // ebuf (E x 4B = 4.8MB) aliases hb: fully consumed by csr_bucket before
    // the first gin_fused writes hb (same stream, serial).
    unsigned* ebuf  = (unsigned*)hb;

    float* class_out = (float*)d_out;
    float* scores    = class_out + GG * NCC;

    // ---- weight prep + x->bf16 (independent of graph pipeline) ----
    prep_edge<<<(6 * 8 * 512 + 4 * 4 * 512 + NCC * 128 + 255) / 256, 256, 0, stream>>>(
        ep_W1, ep_b1, ep_W2, comp_emb, W1b_p, W2_p, pc);
    prep_enc<<<(22528 + 255) / 256, 256, 0, stream>>>(c1_W1, c1_W2, cs_W1, cs_W2, enc);
    x2b_kernel<<<2048, 256, 0, stream>>>(x, xb, N_ * 32);

    // ---- binned CSR build (packed 4B edges) ----
    hipMemsetAsync(bcnt, 0, 2048, stream);
    hipMemsetAsync(nbr + E_, 0, 128 * 4, stream);
    bin_hist<<<1024, 256, 0, stream>>>(dst, bcnt, E_);
    bin_scan<<<1, 256, 0, stream>>>(bcnt, bbase, bpos, NB, E_);
    bin_scatter<<<(E_ + 4095) / 4096, 256, 0, stream>>>(src, dst, bpos, ebuf, E_);
    csr_bucket<<<NB, 256, 0, stream>>>(ebuf, bbase, rowptr, nbr, N_, NB);

    // ---- pool accumulators ----
    hipMemsetAsync(gsum, 0, (size_t)GG * DD * 4, stream);
    gcnt_bs<<<1, GG, 0, stream>>>(batch, gcnt_i, N_);

    // ---- GIN layers (fused gather + MFMA MLP + fused pool) ----
    const int gblk = (N_ + 31) / 32;
    gin_fused<32><<<gblk, 512, 0, stream>>>(
        xb, rowptr, nbr,
        enc + 0, c1_b1, enc + 2048, c1_b2,
        c1_g, c1_be, c1_m, c1_v, c1_eps, hb + 0, batch, gsum, 0, N_);
    gin_fused<64><<<gblk, 512, 0, stream>>>(
        (const unsigned short*)hb + 0, rowptr, nbr,
        enc + 6144, cs_b1 + 0, enc + 10240, cs_b2 + 0,
        cs_g + 0, cs_be + 0, cs_m + 0, cs_v + 0, cs_eps + 0, hb + 64, batch, gsum, 64, N_);
    gin_fused<64><<<gblk, 512, 0, stream>>>(
        (const unsigned short*)hb + 64, rowptr, nbr,
        enc + 14336, cs_b1 + 64, enc + 18432, cs_b2 + 64,
        cs_g + 64, cs_be + 64, cs_m + 64, cs_v + 64, cs_eps + 1, hb + 128, batch, gsum, 128, N_);

    // ---- head ----
    head_kernel<<<GG, 256, 0, stream>>>(gsum, gcnt_i, nc_W1, nc_b1, nc_W2, nc_b2,
                                        nc_W3, nc_b3, nc_W4, nc_b4, class_out, comp_idx);

    // ---- edge prediction (MFMA) ----
    edge_mfma<<<(C_ + 63) / 64, 256, 0, stream>>>(
        cand, batch, comp_idx, (const short*)hb, W1b_p, W2_p, pc, ep_W3, ep_b3, scores, C_);
}

// Round 15
// 249.204 us; speedup vs baseline: 1.2504x; 1.1507x over previous
//
#include <hip/hip_runtime.h>
#include <hip/hip_bf16.h>

// Problem constants (MultiTaskFEGIN): N=100000, E=1200000, F=32, H=64, L=3,
// G=256, C=200000, NC=10, D=L*H=192.

#define GG 256
#define NCC 10
#define DD 192
#define BSH 9          // bucket shift: 512 nodes/bucket (NB=196)

#define PE_BLK 133     // prep_edge: 24576+8192+1280 = 34048 items
#define EN_BLK 88      // prep_enc: 22528 items
#define XB_BLK 512     // x2b grid-stride blocks

typedef short bf16x8 __attribute__((ext_vector_type(8)));
typedef float f32x4  __attribute__((ext_vector_type(4)));

__device__ inline unsigned short f2bf_u(float x) {
    __hip_bfloat16 h = __float2bfloat16(x);
    return *reinterpret_cast<unsigned short*>(&h);
}
__device__ inline float bf2f(unsigned short u) {
    return __uint_as_float(((unsigned int)u) << 16);
}

// ---------------------------------------------------------------------------
// prep_all (1 launch): edge-weight packing + pc, encoder-weight packing,
// x->bf16, bcnt zero + nbr pad zero. Block ranges select the job.
// ---------------------------------------------------------------------------
__global__ void prep_all(
    const float* __restrict__ epW1, const float* __restrict__ epb1,
    const float* __restrict__ epW2, const float* __restrict__ comp_emb,
    unsigned short* __restrict__ W1b_p, unsigned short* __restrict__ W2_p,
    float* __restrict__ pc,
    const float* __restrict__ c1W1, const float* __restrict__ c1W2,
    const float* __restrict__ csW1, const float* __restrict__ csW2,
    unsigned short* __restrict__ enc,
    const float* __restrict__ x, unsigned short* __restrict__ xb, int nx4,
    int* __restrict__ bcnt, int* __restrict__ nbrpad) {
    const int b = blockIdx.x, t = threadIdx.x;
    if (b < PE_BLK) {
        int idx = b * 256 + t;
        const int S1 = 6 * 8 * 512;
        const int S2 = 4 * 4 * 512;
        if (idx < S1) {
            int frag = idx >> 9;
            int lane = (idx >> 3) & 63;
            int j = idx & 7;
            int kstep = frag >> 3, nt = frag & 7;
            int k = kstep * 32 + ((lane >> 4) << 3) + j;
            int n = nt * 16 + (lane & 15);
            W1b_p[idx] = f2bf_u(epW1[(192 + k) * 128 + n]);
        } else if (idx < S1 + S2) {
            int i2 = idx - S1;
            int frag = i2 >> 9;
            int lane = (i2 >> 3) & 63;
            int j = i2 & 7;
            int kstep = frag >> 2, nt = frag & 3;
            int k = kstep * 32 + ((lane >> 4) << 3) + j;
            int n = nt * 16 + (lane & 15);
            W2_p[i2] = f2bf_u(epW2[k * 64 + n]);
        } else if (idx < S1 + S2 + NCC * 128) {
            int i3 = idx - (S1 + S2);
            int ci = i3 >> 7, col = i3 & 127;
            float a = epb1[col];
            for (int k = 0; k < DD; ++k) a += comp_emb[ci * DD + k] * epW1[k * 128 + col];
            pc[i3] = a;
        }
    } else if (b < PE_BLK + EN_BLK) {
        int idx = (b - PE_BLK) * 256 + t;
        if (idx < 22528) {
            const float* W; int rel;
            if (idx < 2048)       { W = c1W1;        rel = idx; }
            else if (idx < 6144)  { W = c1W2;        rel = idx - 2048; }
            else if (idx < 10240) { W = csW1;        rel = idx - 6144; }
            else if (idx < 14336) { W = csW2;        rel = idx - 10240; }
            else if (idx < 18432) { W = csW1 + 4096; rel = idx - 14336; }
            else                  { W = csW2 + 4096; rel = idx - 18432; }
            int frag = rel >> 9;
            int lane = (rel >> 3) & 63;
            int j = rel & 7;
            int ks = frag >> 2, nt = frag & 3;
            int k = ks * 32 + ((lane >> 4) << 3) + j;
            int n = nt * 16 + (lane & 15);
            enc[idx] = f2bf_u(W[k * 64 + n]);
        }
    } else if (b < PE_BLK + EN_BLK + XB_BLK) {
        for (int i = (b - PE_BLK - EN_BLK) * 256 + t; i < nx4; i += XB_BLK * 256) {
            float4 v = *(const float4*)(x + i * 4);
            ushort4 u;
            u.x = f2bf_u(v.x); u.y = f2bf_u(v.y); u.z = f2bf_u(v.z); u.w = f2bf_u(v.w);
            *(ushort4*)(xb + i * 4) = u;
        }
    } else {
        bcnt[t] = 0; bcnt[t + 256] = 0;
        if (t < 128) nbrpad[t] = 0;
    }
}

// ---------------------------------------------------------------------------
// Binned CSR build: packed (src<<BSH)|dst_local ints; 512-node buckets so
// scatter runs are ~84B (vs 42B at BSH=8 - sub-sector writeback waste).
// ---------------------------------------------------------------------------
__global__ void bin_hist(const int* __restrict__ dst, int* __restrict__ bcnt, int E_) {
    __shared__ int h[512];
    const int t = threadIdx.x;
    h[t] = 0; h[t + 256] = 0;
    __syncthreads();
    for (int e = blockIdx.x * 256 + t; e < E_; e += gridDim.x * 256)
        atomicAdd(&h[dst[e] >> BSH], 1);
    __syncthreads();
    if (h[t]) atomicAdd(&bcnt[t], h[t]);
    if (h[t + 256]) atomicAdd(&bcnt[t + 256], h[t + 256]);
}

// scan_misc (1 launch): block 0 = bucket exclusive scan; block 1 = gcnt by
// binary search; blocks 2.. = zero gsum.
__global__ void scan_misc(const int* __restrict__ bcnt, int* __restrict__ bbase,
                          int* __restrict__ bpos, int NB, int E_,
                          const int* __restrict__ batch, int* __restrict__ gcnt_i,
                          float* __restrict__ gsum, int N_) {
    const int b = blockIdx.x, t = threadIdx.x;
    if (b == 0) {
        __shared__ int ps[256];
        int v0 = (2 * t < NB) ? bcnt[2 * t] : 0;
        int v1 = (2 * t + 1 < NB) ? bcnt[2 * t + 1] : 0;
        int pv = v0 + v1;
        ps[t] = pv;
        __syncthreads();
        for (int off = 1; off < 256; off <<= 1) {
            int x = (t >= off) ? ps[t - off] : 0;
            __syncthreads();
            ps[t] += x;
            __syncthreads();
        }
        const int excl = ps[t] - pv;
        if (2 * t < NB)     { bbase[2 * t] = excl;          bpos[2 * t] = excl; }
        if (2 * t + 1 < NB) { bbase[2 * t + 1] = excl + v0; bpos[2 * t + 1] = excl + v0; }
        if (t == 0) bbase[NB] = E_;
    } else if (b == 1) {
        __shared__ int lbs[GG + 1];
        int lo = 0, hi = N_;
        while (lo < hi) {
            int mid = (lo + hi) >> 1;
            if (batch[mid] < t) lo = mid + 1; else hi = mid;
        }
        lbs[t] = lo;
        if (t == 0) lbs[GG] = N_;
        __syncthreads();
        gcnt_i[t] = lbs[t + 1] - lbs[t];
    } else {
        int i = (b - 2) * 256 + t;
        if (i < GG * DD) gsum[i] = 0.f;
    }
}

// 4096 edges/block (16/thread): rank in LDS, one range-claim per bucket.
__global__ __launch_bounds__(256) void bin_scatter(
    const int* __restrict__ src, const int* __restrict__ dst,
    int* __restrict__ bpos, unsigned* __restrict__ ebuf, int E_) {
    __shared__ int h[512];
    __shared__ int base[512];
    const int t = threadIdx.x;
    const int e0 = blockIdx.x * 4096;
    h[t] = 0; h[t + 256] = 0;
    __syncthreads();
    int myb[16], myr[16];
    unsigned pk[16];
    #pragma unroll
    for (int u = 0; u < 16; ++u) {
        int e = e0 + t + u * 256;
        if (e < E_) {
            int d = dst[e];
            myb[u] = d >> BSH;
            pk[u] = ((unsigned)src[e] << BSH) | (unsigned)(d & ((1 << BSH) - 1));
            myr[u] = atomicAdd(&h[myb[u]], 1);
        } else myb[u] = -1;
    }
    __syncthreads();
    if (h[t]) base[t] = atomicAdd(&bpos[t], h[t]);
    if (h[t + 256]) base[t + 256] = atomicAdd(&bpos[t + 256], h[t + 256]);
    __syncthreads();
    #pragma unroll
    for (int u = 0; u < 16; ++u)
        if (myb[u] >= 0)
            ebuf[base[myb[u]] + myr[u]] = pk[u];
}

// One block per 512-node bucket: 512-bin histogram -> pair-scan -> rowptr -> nbr.
__global__ __launch_bounds__(256) void csr_bucket(
    const unsigned* __restrict__ ebuf, const int* __restrict__ bbase,
    int* __restrict__ rowptr, int* __restrict__ nbr, int N_, int NB) {
    __shared__ int lh[512];
    __shared__ int lx[512];
    __shared__ int ps[256];
    const int b = blockIdx.x;
    const int t = threadIdx.x;
    const int ebase = bbase[b], eend = bbase[b + 1];
    const int ecnt = eend - ebase;
    const int n0 = b << BSH;
    const unsigned M = (1 << BSH) - 1;

    for (int i = t; i < 512; i += 256) lh[i] = 0;
    __syncthreads();
    for (int i = t; i < ecnt; i += 256)
        atomicAdd(&lh[ebuf[ebase + i] & M], 1);
    __syncthreads();

    int pv = lh[2 * t] + lh[2 * t + 1];
    ps[t] = pv;
    __syncthreads();
    for (int off = 1; off < 256; off <<= 1) {
        int x = (t >= off) ? ps[t - off] : 0;
        __syncthreads();
        ps[t] += x;
        __syncthreads();
    }
    const int excl = ps[t] - pv;
    lx[2 * t] = excl;
    lx[2 * t + 1] = excl + lh[2 * t];
    __syncthreads();

    for (int i = t; i < 512; i += 256) {
        int n = n0 + i;
        if (n < N_) rowptr[n] = ebase + lx[i];
    }
    if (b == NB - 1 && t == 0) rowptr[N_] = eend;
    __syncthreads();
    for (int i = t; i < 512; i += 256) lh[i] = lx[i];
    __syncthreads();
    for (int i = t; i < ecnt; i += 256) {
        unsigned p = ebuf[ebase + i];
        int r = atomicAdd(&lh[p & M], 1);
        nbr[ebase + r] = (int)(p >> BSH);
    }
}

// ---------------------------------------------------------------------------
// Fused GIN layer (R14, unchanged): 2-deep pipelined running-sum gather ->
// MFMA MLP -> BN -> hb slice + fused pool.
// ---------------------------------------------------------------------------
#define SWZ(row, byte) ((byte) ^ (((row) & 7) << 4))

#define GSTEP(VCUR, VNXT)                                                     \
    _Pragma("unroll")                                                         \
    for (int u = 0; u < 16; ++u)                                              \
        VNXT[u] = bf2f(*(const unsigned short*)(hbase + (unsigned)idx[u] * (unsigned)RSB + lane2)); \
    _Pragma("unroll")                                                         \
    for (int u = 0; u < 16; ++u) idx[u] = nbp[k + 32 + u];                    \
    {                                                                         \
        float runk = run;                                                     \
        _Pragma("unroll")                                                     \
        for (int u = 0; u < 16; ++u) run += VCUR[u];                          \
        if ((unsigned)(e1 - k) < 16u) { float tt = runk;                      \
            _Pragma("unroll")                                                 \
            for (int u = 0; u < 16; ++u) tt += (u < e1 - k) ? VCUR[u] : 0.f;  \
            s0 = tt; }                                                        \
        if ((unsigned)(e2 - k) < 16u) { float tt = runk;                      \
            _Pragma("unroll")                                                 \
            for (int u = 0; u < 16; ++u) tt += (u < e2 - k) ? VCUR[u] : 0.f;  \
            s1 = tt; }                                                        \
        if ((unsigned)(e3 - k) < 16u) { float tt = runk;                      \
            _Pragma("unroll")                                                 \
            for (int u = 0; u < 16; ++u) tt += (u < e3 - k) ? VCUR[u] : 0.f;  \
            s2 = tt; }                                                        \
        if ((unsigned)(cnt - k) < 16u) { float tt = runk;                     \
            _Pragma("unroll")                                                 \
            for (int u = 0; u < 16; ++u) tt += (u < cnt - k) ? VCUR[u] : 0.f; \
            s3 = tt; }                                                        \
    }                                                                         \
    k += 16;                                                                  \
    if (k > cnt) break;

template<int K>
__global__ __launch_bounds__(512) void gin_fused(
    const unsigned short* __restrict__ hin_b,  // bf16 rows: stride DD (K=64) / 32 (K=32)
    const int* __restrict__ rowptr, const int* __restrict__ nbr,
    const unsigned short* __restrict__ W1p, const float* __restrict__ b1,
    const unsigned short* __restrict__ W2p, const float* __restrict__ b2,
    const float* __restrict__ gamma, const float* __restrict__ beta,
    const float* __restrict__ mean, const float* __restrict__ var,
    const float* __restrict__ eps_p,
    __hip_bfloat16* __restrict__ out_b,        // slice ptr, stride DD
    const int* __restrict__ batch, float* __restrict__ gsum, int soff,
    int N_) {
    __shared__ char s_agg[32 * 128];   // bf16 [32 nodes][64 k], XOR-swizzled
    __shared__ char s_h1[32 * 128];
    __shared__ char s_out[32 * 128];
    __shared__ int sb[32];

    const int t = threadIdx.x;
    const int lane = t & 63;
    const int w = t >> 6;
    const int node0 = blockIdx.x * 32;
    const int nb = w * 4;

    if (t < 32) sb[t] = (node0 + t < N_) ? batch[node0 + t] : -1;

    const float eps1 = 1.0f + eps_p[0];

    // ---- combined-span gather for this wave's 4 consecutive nodes ----
    const int n0w = node0 + nb;
    const int rp0 = __builtin_amdgcn_readfirstlane(rowptr[min(n0w + 0, N_)]);
    const int rp1 = __builtin_amdgcn_readfirstlane(rowptr[min(n0w + 1, N_)]);
    const int rp2 = __builtin_amdgcn_readfirstlane(rowptr[min(n0w + 2, N_)]);
    const int rp3 = __builtin_amdgcn_readfirstlane(rowptr[min(n0w + 3, N_)]);
    const int rp4 = __builtin_amdgcn_readfirstlane(rowptr[min(n0w + 4, N_)]);
    const int cnt = rp4 - rp0;
    const int e1 = rp1 - rp0, e2 = rp2 - rp0, e3 = rp3 - rp0;
    const int* nbp = nbr + rp0;

    const int RSB = (K == 64) ? DD * 2 : 64;       // gather row stride (bytes)
    const int OST = (K == 64) ? DD : 32;           // own-row stride (elems)
    const char* hbase = (const char*)hin_b;
    const unsigned lane2 = (unsigned)(lane & (K - 1)) * 2u;

    int idx[16];
    float vA[16], vB[16];
    float run = 0.f, s0 = 0.f, s1 = 0.f, s2 = 0.f, s3 = 0.f;
    #pragma unroll
    for (int u = 0; u < 16; ++u) idx[u] = nbp[u];
    #pragma unroll
    for (int u = 0; u < 16; ++u)
        vA[u] = bf2f(*(const unsigned short*)(hbase + (unsigned)idx[u] * (unsigned)RSB + lane2));
    #pragma unroll
    for (int u = 0; u < 16; ++u) idx[u] = nbp[16 + u];
    for (int k = 0;;) {
        GSTEP(vA, vB)
        GSTEP(vB, vA)
    }
    float a0 = s0, a1 = s1 - s0, a2 = s2 - s1, a3 = s3 - s2;
    {
        const unsigned short* hbp = hin_b + (lane & (K - 1));
        if (n0w + 0 < N_) a0 += eps1 * bf2f(hbp[(size_t)(n0w + 0) * OST]);
        if (n0w + 1 < N_) a1 += eps1 * bf2f(hbp[(size_t)(n0w + 1) * OST]);
        if (n0w + 2 < N_) a2 += eps1 * bf2f(hbp[(size_t)(n0w + 2) * OST]);
        if (n0w + 3 < N_) a3 += eps1 * bf2f(hbp[(size_t)(n0w + 3) * OST]);
    }
    if (K == 64 || lane < 32) {
        const int kd = lane & (K - 1);
        *(unsigned short*)(s_agg + SWZ(nb + 0, (nb + 0) * 128 + kd * 2)) = f2bf_u(a0);
        *(unsigned short*)(s_agg + SWZ(nb + 1, (nb + 1) * 128 + kd * 2)) = f2bf_u(a1);
        *(unsigned short*)(s_agg + SWZ(nb + 2, (nb + 2) * 128 + kd * 2)) = f2bf_u(a2);
        *(unsigned short*)(s_agg + SWZ(nb + 3, (nb + 3) * 128 + kd * 2)) = f2bf_u(a3);
    }
    __syncthreads();

    // ---- GEMM1: [32 x K] @ [K x 64] via MFMA; wave w -> C tile (mt, nt) ----
    const int mt = w >> 2, nt = w & 3;
    const int arow = mt * 16 + (lane & 15);
    const int col = nt * 16 + (lane & 15);
    f32x4 c1v = (f32x4){0.f, 0.f, 0.f, 0.f};
    #pragma unroll
    for (int ks = 0; ks < K / 32; ++ks) {
        bf16x8 a = *(const bf16x8*)(s_agg + SWZ(arow, arow * 128 + ks * 64 + ((lane >> 4) << 4)));
        bf16x8 b = *(const bf16x8*)(W1p + (((ks << 2) + nt) << 9) + (lane << 3));
        c1v = __builtin_amdgcn_mfma_f32_16x16x32_bf16(a, b, c1v, 0, 0, 0);
    }
    {
        const float bb1 = b1[col];
        #pragma unroll
        for (int reg = 0; reg < 4; ++reg) {
            int row = mt * 16 + ((lane >> 4) << 2) + reg;
            float v = fmaxf(c1v[reg] + bb1, 0.f);
            *(unsigned short*)(s_h1 + SWZ(row, row * 128 + col * 2)) = f2bf_u(v);
        }
    }
    __syncthreads();

    // ---- GEMM2: [32 x 64] @ [64 x 64] + BN epilogue ----
    f32x4 c2v = (f32x4){0.f, 0.f, 0.f, 0.f};
    #pragma unroll
    for (int ks = 0; ks < 2; ++ks) {
        bf16x8 a = *(const bf16x8*)(s_h1 + SWZ(arow, arow * 128 + ks * 64 + ((lane >> 4) << 4)));
        bf16x8 b = *(const bf16x8*)(W2p + (((ks << 2) + nt) << 9) + (lane << 3));
        c2v = __builtin_amdgcn_mfma_f32_16x16x32_bf16(a, b, c2v, 0, 0, 0);
    }
    {
        const float bb2 = b2[col];
        const float ga = gamma[col], bet = beta[col], mu = mean[col];
        const float iv = rsqrtf(var[col] + 1e-5f);
        #pragma unroll
        for (int reg = 0; reg < 4; ++reg) {
            int row = mt * 16 + ((lane >> 4) << 2) + reg;
            float v = fmaxf(c2v[reg] + bb2, 0.f);
            v = ga * (v - mu) * iv + bet;
            *(unsigned short*)(s_out + SWZ(row, row * 128 + col * 2)) = f2bf_u(v);
        }
    }
    __syncthreads();

    // ---- coalesced copy out: 32 rows x 128B, 16 threads/row x 8B ----
    {
        int r = t >> 4, c8 = t & 15;
        int node = node0 + r;
        if (node < N_) {
            ushort4 v = *(const ushort4*)(s_out + SWZ(r, r * 128 + c8 * 8));
            *(ushort4*)((unsigned short*)out_b + (size_t)node * DD + c8 * 4) = v;
        }
    }

    // ---- fused mean-pool accumulation for this slice (batch sorted) ----
    if (t < 256) {
        const int d = t & 63;
        const int rg = t >> 6;
        float acc = 0.f;
        int curg = sb[rg * 8];
        #pragma unroll
        for (int r = rg * 8; r < rg * 8 + 8; ++r) {
            int g = sb[r];
            if (g != curg) {
                if (curg >= 0) atomicAdd(&gsum[curg * DD + soff + d], acc);
                acc = 0.f; curg = g;
            }
            if (g >= 0)
                acc += bf2f(*(const unsigned short*)(s_out + SWZ(r, r * 128 + d * 2)));
        }
        if (curg >= 0) atomicAdd(&gsum[curg * DD + soff + d], acc);
    }
}

// ---------------------------------------------------------------------------
// Classification head: one block per graph (fp32 throughout).
// ---------------------------------------------------------------------------
__global__ void head_kernel(const float* __restrict__ gsum, const int* __restrict__ gcnt_i,
                            const float* __restrict__ W1, const float* __restrict__ b1,
                            const float* __restrict__ W2, const float* __restrict__ b2,
                            const float* __restrict__ W3, const float* __restrict__ b3,
                            const float* __restrict__ W4, const float* __restrict__ b4,
                            float* __restrict__ class_out, int* __restrict__ comp_idx) {
    const int g = blockIdx.x;
    const int t = threadIdx.x;
    __shared__ float ge[DD], h1[128], h2[64], h3[64], logits[NCC];

    const float c = fmaxf((float)gcnt_i[g], 1.0f);
    if (t < DD) ge[t] = gsum[g * DD + t] / c;
    __syncthreads();

    if (t < 128) {
        float a = b1[t];
        #pragma unroll 4
        for (int k = 0; k < DD; ++k) a += ge[k] * W1[k * 128 + t];
        h1[t] = fmaxf(a, 0.0f);
    }
    __syncthreads();
    if (t < 64) {
        float a = b2[t];
        #pragma unroll 4
        for (int k = 0; k < 128; ++k) a += h1[k] * W2[k * 64 + t];
        h2[t] = fmaxf(a, 0.0f);
    }
    __syncthreads();
    if (t < 64) {
        float a = b3[t];
        #pragma unroll 4
        for (int k = 0; k < 64; ++k) a += h2[k] * W3[k * 64 + t];
        h3[t] = fmaxf(a, 0.0f);
    }
    __syncthreads();
    if (t < NCC) {
        float a = b4[t];
        #pragma unroll
        for (int k = 0; k < 64; ++k) a += h3[k] * W4[k * NCC + t];
        logits[t] = a;
    }
    __syncthreads();
    if (t == 0) {
        float mx = logits[0]; int am = 0;
        for (int j = 1; j < NCC; ++j) if (logits[j] > mx) { mx = logits[j]; am = j; }
        float se = 0.0f;
        for (int j = 0; j < NCC; ++j) se += expf(logits[j] - mx);
        float lse = logf(se);
        for (int j = 0; j < NCC; ++j) class_out[g * NCC + j] = logits[j] - mx - lse;
        comp_idx[g] = am;
    }
}

// ---------------------------------------------------------------------------
// edge_mfma (R10, unchanged): 64 candidates / 256-thread block, col-split.
// ---------------------------------------------------------------------------
__global__ __launch_bounds__(256, 5) void edge_mfma(
    const int* __restrict__ cand, const int* __restrict__ batch,
    const int* __restrict__ comp_idx, const short* __restrict__ hb,
    const unsigned short* __restrict__ W1b_p, const unsigned short* __restrict__ W2_p,
    const float* __restrict__ pc, const float* __restrict__ W3,
    const float* __restrict__ b3, float* __restrict__ scores, int C_) {
    __shared__ char s_buf[64 * 384];   // de (24KB); h1 reuses first 16KB
    __shared__ float s_part[4][64];
    __shared__ int s_node[64];
    __shared__ int s_ci[64];
    __shared__ float s_w3[64];

    const int t = threadIdx.x;
    const int lane = t & 63;
    const int w = t >> 6;
    const int c0 = blockIdx.x * 64;

    if (t < 64) {
        int c = c0 + t;
        int node = (c < C_) ? cand[c] : cand[0];
        s_node[t] = node;
        s_ci[t] = comp_idx[batch[node]];
        s_w3[t] = W3[t];
    }
    __syncthreads();

    for (int i = t; i < 64 * 24; i += 256) {
        int r = i / 24, c8 = i - r * 24;
        bf16x8 v = *(const bf16x8*)(hb + (size_t)s_node[r] * DD + c8 * 8);
        *(bf16x8*)(s_buf + SWZ(r, r * 384 + c8 * 16)) = v;
    }
    __syncthreads();

    f32x4 acc1[4][2];
    #pragma unroll
    for (int rt = 0; rt < 4; ++rt)
        #pragma unroll
        for (int b = 0; b < 2; ++b) acc1[rt][b] = (f32x4){0.f, 0.f, 0.f, 0.f};
    #pragma unroll
    for (int ks = 0; ks < 6; ++ks) {
        bf16x8 b0 = *(const bf16x8*)(W1b_p + ((ks * 8 + 2 * w + 0) << 9) + (lane << 3));
        bf16x8 b1f = *(const bf16x8*)(W1b_p + ((ks * 8 + 2 * w + 1) << 9) + (lane << 3));
        #pragma unroll
        for (int rt = 0; rt < 4; ++rt) {
            int arow = rt * 16 + (lane & 15);
            bf16x8 a = *(const bf16x8*)(s_buf + SWZ(arow, arow * 384 + ks * 64 + ((lane >> 4) << 4)));
            acc1[rt][0] = __builtin_amdgcn_mfma_f32_16x16x32_bf16(a, b0, acc1[rt][0], 0, 0, 0);
            acc1[rt][1] = __builtin_amdgcn_mfma_f32_16x16x32_bf16(a, b1f, acc1[rt][1], 0, 0, 0);
        }
    }
    __syncthreads();

    #pragma unroll
    for (int rt = 0; rt < 4; ++rt) {
        #pragma unroll
        for (int reg = 0; reg < 4; ++reg) {
            int row = rt * 16 + ((lane >> 4) << 2) + reg;
            int ci = s_ci[row];
            #pragma unroll
            for (int b = 0; b < 2; ++b) {
                int col = (2 * w + b) * 16 + (lane & 15);
                float v = fmaxf(acc1[rt][b][reg] + pc[ci * 128 + col], 0.f);
                *(unsigned short*)(s_buf + SWZ(row, row * 256 + col * 2)) = f2bf_u(v);
            }
        }
    }
    __syncthreads();

    f32x4 acc2[4];
    #pragma unroll
    for (int rt = 0; rt < 4; ++rt) acc2[rt] = (f32x4){0.f, 0.f, 0.f, 0.f};
    #pragma unroll
    for (int ks = 0; ks < 4; ++ks) {
        bf16x8 b = *(const bf16x8*)(W2_p + ((ks * 4 + w) << 9) + (lane << 3));
        #pragma unroll
        for (int rt = 0; rt < 4; ++rt) {
            int arow = rt * 16 + (lane & 15);
            bf16x8 a = *(const bf16x8*)(s_buf + SWZ(arow, arow * 256 + ks * 64 + ((lane >> 4) << 4)));
            acc2[rt] = __builtin_amdgcn_mfma_f32_16x16x32_bf16(a, b, acc2[rt], 0, 0, 0);
        }
    }

    {
        const float w3v = s_w3[w * 16 + (lane & 15)];
        #pragma unroll
        for (int rt = 0; rt < 4; ++rt) {
            #pragma unroll
            for (int reg = 0; reg < 4; ++reg) {
                float p = fmaxf(acc2[rt][reg], 0.f) * w3v;
                p += __shfl_xor(p, 1);
                p += __shfl_xor(p, 2);
                p += __shfl_xor(p, 4);
                p += __shfl_xor(p, 8);
                if ((lane & 15) == 0)
                    s_part[w][rt * 16 + ((lane >> 4) << 2) + reg] = p;
            }
        }
    }
    __syncthreads();

    if (t < 64) {
        int c = c0 + t;
        if (c < C_) {
            float p = s_part[0][t] + s_part[1][t] + s_part[2][t] + s_part[3][t] + b3[0];
            scores[c] = 1.0f / (1.0f + expf(-p));
        }
    }
}

// ---------------------------------------------------------------------------
extern "C" void kernel_launch(void* const* d_in, const int* in_sizes, int n_in,
                              void* d_out, int out_size, void* d_ws, size_t ws_size,
                              hipStream_t stream) {
    const float* x        = (const float*)d_in[0];
    const int*   ei       = (const int*)d_in[1];
    const int*   batch    = (const int*)d_in[2];
    const int*   cand     = (const int*)d_in[3];
    const float* c1_W1    = (const float*)d_in[4];
    const float* c1_b1    = (const float*)d_in[5];
    const float* c1_W2    = (const float*)d_in[6];
    const float* c1_b2    = (const float*)d_in[7];
    const float* c1_g     = (const float*)d_in[8];
    const float* c1_be    = (const float*)d_in[9];
    const float* c1_m     = (const float*)d_in[10];
    const float* c1_v     = (const float*)d_in[11];
    const float* c1_eps   = (const float*)d_in[12];
    const float* cs_W1    = (const float*)d_in[13];
    const float* cs_b1    = (const float*)d_in[14];
    const float* cs_W2    = (const float*)d_in[15];
    const float* cs_b2    = (const float*)d_in[16];
    const float* cs_g     = (const float*)d_in[17];
    const float* cs_be    = (const float*)d_in[18];
    const float* cs_m     = (const float*)d_in[19];
    const float* cs_v     = (const float*)d_in[20];
    const float* cs_eps   = (const float*)d_in[21];
    const float* nc_W1    = (const float*)d_in[22];
    const float* nc_b1    = (const float*)d_in[23];
    const float* nc_W2    = (const float*)d_in[24];
    const float* nc_b2    = (const float*)d_in[25];
    const float* nc_W3    = (const float*)d_in[26];
    const float* nc_b3    = (const float*)d_in[27];
    const float* nc_W4    = (const float*)d_in[28];
    const float* nc_b4    = (const float*)d_in[29];
    const float* comp_emb = (const float*)d_in[30];
    const float* ep_W1    = (const float*)d_in[31];
    const float* ep_b1    = (const float*)d_in[32];
    const float* ep_W2    = (const float*)d_in[33];
    const float* ep_b2    = (const float*)d_in[34];
    const float* ep_W3    = (const float*)d_in[35];
    const float* ep_b3    = (const float*)d_in[36];

    const int N_ = in_sizes[0] / 32;
    const int E_ = in_sizes[1] / 2;
    const int C_ = in_sizes[3];
    const int* src = ei;
    const int* dst = ei + E_;
    const int NB = (N_ + (1 << BSH) - 1) >> BSH;   // 196 buckets of 512 nodes

    char* ws = (char*)d_ws;
    size_t off = 0;
    __hip_bfloat16* hb = (__hip_bfloat16*)(ws + off); off += (size_t)N_ * DD * 2;
    unsigned short* xb = (unsigned short*)(ws + off); off += (size_t)N_ * 32 * 2;
    int*   rowptr   = (int*)(ws + off);   off += (size_t)(N_ + 2) * 4;
    int*   nbr      = (int*)(ws + off);   off += (size_t)(E_ + 128) * 4;
    int*   bcnt     = (int*)(ws + off);   off += 2048;
    int*   bbase    = (int*)(ws + off);   off += 2080;
    int*   bpos     = (int*)(ws + off);   off += 2048;
    float* gsum     = (float*)(ws + off); off += (size_t)GG * DD * 4;
    int*   gcnt_i   = (int*)(ws + off);   off += 1024;
    int*   comp_idx = (int*)(ws + off);   off += 1024;
    float* pc       = (float*)(ws + off); off += NCC * 128 * 4;
    unsigned short* W1b_p = (unsigned short*)(ws + off); off += 6 * 8 * 512 * 2;
    unsigned short* W2_p  = (unsigned short*)(ws + off); off += 4 * 4 * 512 * 2;
    unsigned short* enc   = (unsigned short*)(ws + off); off += 22528 * 2;
    // ebuf (E x 4B = 4.8MB) aliases hb: fully consumed by csr_bucket before
    // the first gin_fused writes hb (same stream, serial).
    unsigned* ebuf  = (unsigned*)hb;

    float* class_out = (float*)d_out;
    float* scores    = class_out + GG * NCC;

    // ---- fused prep: edge/enc weight packing + x2b + zeroing (1 launch) ----
    prep_all<<<PE_BLK + EN_BLK + XB_BLK + 1, 256, 0, stream>>>(
        ep_W1, ep_b1, ep_W2, comp_emb, W1b_p, W2_p, pc,
        c1_W1, c1_W2, cs_W1, cs_W2, enc,
        x, xb, N_ * 32 / 4, bcnt, nbr + E_);

    // ---- binned CSR build ----
    bin_hist<<<256, 256, 0, stream>>>(dst, bcnt, E_);
    scan_misc<<<2 + (GG * DD + 255) / 256, 256, 0, stream>>>(
        bcnt, bbase, bpos, NB, E_, batch, gcnt_i, gsum, N_);
    bin_scatter<<<(E_ + 4095) / 4096, 256, 0, stream>>>(src, dst, bpos, ebuf, E_);
    csr_bucket<<<NB, 256, 0, stream>>>(ebuf, bbase, rowptr, nbr, N_, NB);

    // ---- GIN layers (fused gather + MFMA MLP + fused pool) ----
    const int gblk = (N_ + 31) / 32;
    gin_fused<32><<<gblk, 512, 0, stream>>>(
        xb, rowptr, nbr,
        enc + 0, c1_b1, enc + 2048, c1_b2,
        c1_g, c1_be, c1_m, c1_v, c1_eps, hb + 0, batch, gsum, 0, N_);
    gin_fused<64><<<gblk, 512, 0, stream>>>(
        (const unsigned short*)hb + 0, rowptr, nbr,
        enc + 6144, cs_b1 + 0, enc + 10240, cs_b2 + 0,
        cs_g + 0, cs_be + 0, cs_m + 0, cs_v + 0, cs_eps + 0, hb + 64, batch, gsum, 64, N_);
    gin_fused<64><<<gblk, 512, 0, stream>>>(
        (const unsigned short*)hb + 64, rowptr, nbr,
        enc + 14336, cs_b1 + 64, enc + 18432, cs_b2 + 64,
        cs_g + 64, cs_be + 64, cs_m + 64, cs_v + 64, cs_eps + 1, hb + 128, batch, gsum, 128, N_);

    // ---- head ----
    head_kernel<<<GG, 256, 0, stream>>>(gsum, gcnt_i, nc_W1, nc_b1, nc_W2, nc_b2,
                                        nc_W3, nc_b3, nc_W4, nc_b4, class_out, comp_idx);

    // ---- edge prediction (MFMA) ----
    edge_mfma<<<(C_ + 63) / 64, 256, 0, stream>>>(
        cand, batch, comp_idx, (const short*)hb, W1b_p, W2_p, pc, ep_W3, ep_b3, scores, C_);
}

// Round 16
// 246.101 us; speedup vs baseline: 1.2662x; 1.0126x over previous
//
#include <hip/hip_runtime.h>
#include <hip/hip_bf16.h>

// Problem constants (MultiTaskFEGIN): N=100000, E=1200000, F=32, H=64, L=3,
// G=256, C=200000, NC=10, D=L*H=192.

#define GG 256
#define NCC 10
#define DD 192
#define BSH 9          // bucket shift: 512 nodes/bucket (NB=196)

#define PE_BLK 133     // prep_edge: 24576+8192+1280 = 34048 items
#define EN_BLK 88      // prep_enc: 22528 items
#define XB_BLK 512     // x2b grid-stride blocks
#define HI_BLK 64      // private-histogram blocks (no global atomics)

typedef short bf16x8 __attribute__((ext_vector_type(8)));
typedef float f32x4  __attribute__((ext_vector_type(4)));

__device__ inline unsigned short f2bf_u(float x) {
    __hip_bfloat16 h = __float2bfloat16(x);
    return *reinterpret_cast<unsigned short*>(&h);
}
__device__ inline float bf2f(unsigned short u) {
    return __uint_as_float(((unsigned int)u) << 16);
}

// ---------------------------------------------------------------------------
// prep_all (1 launch): edge-weight packing + pc, encoder-weight packing,
// x->bf16, per-block private dst histograms (-> hist_part, NO global
// atomics), nbr pad zero. Block ranges select the job.
// ---------------------------------------------------------------------------
__global__ void prep_all(
    const float* __restrict__ epW1, const float* __restrict__ epb1,
    const float* __restrict__ epW2, const float* __restrict__ comp_emb,
    unsigned short* __restrict__ W1b_p, unsigned short* __restrict__ W2_p,
    float* __restrict__ pc,
    const float* __restrict__ c1W1, const float* __restrict__ c1W2,
    const float* __restrict__ csW1, const float* __restrict__ csW2,
    unsigned short* __restrict__ enc,
    const float* __restrict__ x, unsigned short* __restrict__ xb, int nx4,
    const int* __restrict__ dst, int E_, int* __restrict__ hist_part,
    int* __restrict__ nbrpad) {
    const int b = blockIdx.x, t = threadIdx.x;
    if (b < PE_BLK) {
        int idx = b * 256 + t;
        const int S1 = 6 * 8 * 512;
        const int S2 = 4 * 4 * 512;
        if (idx < S1) {
            int frag = idx >> 9;
            int lane = (idx >> 3) & 63;
            int j = idx & 7;
            int kstep = frag >> 3, nt = frag & 7;
            int k = kstep * 32 + ((lane >> 4) << 3) + j;
            int n = nt * 16 + (lane & 15);
            W1b_p[idx] = f2bf_u(epW1[(192 + k) * 128 + n]);
        } else if (idx < S1 + S2) {
            int i2 = idx - S1;
            int frag = i2 >> 9;
            int lane = (i2 >> 3) & 63;
            int j = i2 & 7;
            int kstep = frag >> 2, nt = frag & 3;
            int k = kstep * 32 + ((lane >> 4) << 3) + j;
            int n = nt * 16 + (lane & 15);
            W2_p[i2] = f2bf_u(epW2[k * 64 + n]);
        } else if (idx < S1 + S2 + NCC * 128) {
            int i3 = idx - (S1 + S2);
            int ci = i3 >> 7, col = i3 & 127;
            float a = epb1[col];
            for (int k = 0; k < DD; ++k) a += comp_emb[ci * DD + k] * epW1[k * 128 + col];
            pc[i3] = a;
        }
    } else if (b < PE_BLK + EN_BLK) {
        int idx = (b - PE_BLK) * 256 + t;
        if (idx < 22528) {
            const float* W; int rel;
            if (idx < 2048)       { W = c1W1;        rel = idx; }
            else if (idx < 6144)  { W = c1W2;        rel = idx - 2048; }
            else if (idx < 10240) { W = csW1;        rel = idx - 6144; }
            else if (idx < 14336) { W = csW2;        rel = idx - 10240; }
            else if (idx < 18432) { W = csW1 + 4096; rel = idx - 14336; }
            else                  { W = csW2 + 4096; rel = idx - 18432; }
            int frag = rel >> 9;
            int lane = (rel >> 3) & 63;
            int j = rel & 7;
            int ks = frag >> 2, nt = frag & 3;
            int k = ks * 32 + ((lane >> 4) << 3) + j;
            int n = nt * 16 + (lane & 15);
            enc[idx] = f2bf_u(W[k * 64 + n]);
        }
    } else if (b < PE_BLK + EN_BLK + XB_BLK) {
        for (int i = (b - PE_BLK - EN_BLK) * 256 + t; i < nx4; i += XB_BLK * 256) {
            float4 v = *(const float4*)(x + i * 4);
            ushort4 u;
            u.x = f2bf_u(v.x); u.y = f2bf_u(v.y); u.z = f2bf_u(v.z); u.w = f2bf_u(v.w);
            *(ushort4*)(xb + i * 4) = u;
        }
    } else if (b < PE_BLK + EN_BLK + XB_BLK + HI_BLK) {
        __shared__ int h[512];
        const int hbk = b - (PE_BLK + EN_BLK + XB_BLK);
        h[t] = 0; h[t + 256] = 0;
        __syncthreads();
        for (int e = hbk * 256 + t; e < E_; e += HI_BLK * 256)
            atomicAdd(&h[dst[e] >> BSH], 1);
        __syncthreads();
        hist_part[hbk * 512 + t] = h[t];
        hist_part[hbk * 512 + t + 256] = h[t + 256];
    } else {
        if (t < 128) nbrpad[t] = 0;
    }
}

// ---------------------------------------------------------------------------
// scan_misc (1 launch): block 0 = reduce hist_part + bucket exclusive scan;
// block 1 = gcnt by binary search; blocks 2.. = zero gsum.
// ---------------------------------------------------------------------------
__global__ void scan_misc(const int* __restrict__ hist_part, int* __restrict__ bbase,
                          int* __restrict__ bpos, int NB, int E_,
                          const int* __restrict__ batch, int* __restrict__ gcnt_i,
                          float* __restrict__ gsum, int N_) {
    const int b = blockIdx.x, t = threadIdx.x;
    if (b == 0) {
        __shared__ int ps[256];
        int v0 = 0, v1 = 0;
        #pragma unroll 4
        for (int p = 0; p < HI_BLK; ++p) {
            v0 += hist_part[p * 512 + 2 * t];
            v1 += hist_part[p * 512 + 2 * t + 1];
        }
        int pv = v0 + v1;
        ps[t] = pv;
        __syncthreads();
        for (int off = 1; off < 256; off <<= 1) {
            int x = (t >= off) ? ps[t - off] : 0;
            __syncthreads();
            ps[t] += x;
            __syncthreads();
        }
        const int excl = ps[t] - pv;
        if (2 * t < NB)     { bbase[2 * t] = excl;          bpos[2 * t] = excl; }
        if (2 * t + 1 < NB) { bbase[2 * t + 1] = excl + v0; bpos[2 * t + 1] = excl + v0; }
        if (t == 0) bbase[NB] = E_;
    } else if (b == 1) {
        __shared__ int lbs[GG + 1];
        int lo = 0, hi = N_;
        while (lo < hi) {
            int mid = (lo + hi) >> 1;
            if (batch[mid] < t) lo = mid + 1; else hi = mid;
        }
        lbs[t] = lo;
        if (t == 0) lbs[GG] = N_;
        __syncthreads();
        gcnt_i[t] = lbs[t + 1] - lbs[t];
    } else {
        int i = (b - 2) * 256 + t;
        if (i < GG * DD) gsum[i] = 0.f;
    }
}

// ---------------------------------------------------------------------------
// bin_scatter: 4096 edges/block (16/thread), rank in LDS, one range-claim
// per bucket, packed (src<<BSH)|dst_local 4B writes in contiguous runs.
// ---------------------------------------------------------------------------
__global__ __launch_bounds__(256) void bin_scatter(
    const int* __restrict__ src, const int* __restrict__ dst,
    int* __restrict__ bpos, unsigned* __restrict__ ebuf, int E_) {
    __shared__ int h[512];
    __shared__ int base[512];
    const int t = threadIdx.x;
    const int e0 = blockIdx.x * 4096;
    h[t] = 0; h[t + 256] = 0;
    __syncthreads();
    int myb[16], myr[16];
    unsigned pk[16];
    #pragma unroll
    for (int u = 0; u < 16; ++u) {
        int e = e0 + t + u * 256;
        if (e < E_) {
            int d = dst[e];
            myb[u] = d >> BSH;
            pk[u] = ((unsigned)src[e] << BSH) | (unsigned)(d & ((1 << BSH) - 1));
            myr[u] = atomicAdd(&h[myb[u]], 1);
        } else myb[u] = -1;
    }
    __syncthreads();
    if (h[t]) base[t] = atomicAdd(&bpos[t], h[t]);
    if (h[t + 256]) base[t + 256] = atomicAdd(&bpos[t + 256], h[t + 256]);
    __syncthreads();
    #pragma unroll
    for (int u = 0; u < 16; ++u)
        if (myb[u] >= 0)
            ebuf[base[myb[u]] + myr[u]] = pk[u];
}

// ---------------------------------------------------------------------------
// csr_bucket: one 512-thread block per 512-node bucket (1 thread/bin):
// histogram -> 512-wide scan -> rowptr -> nbr.
// ---------------------------------------------------------------------------
__global__ __launch_bounds__(512) void csr_bucket(
    const unsigned* __restrict__ ebuf, const int* __restrict__ bbase,
    int* __restrict__ rowptr, int* __restrict__ nbr, int N_, int NB) {
    __shared__ int lh[512];
    __shared__ int lx[512];
    const int b = blockIdx.x;
    const int t = threadIdx.x;
    const int ebase = bbase[b], eend = bbase[b + 1];
    const int ecnt = eend - ebase;
    const int n0 = b << BSH;
    const unsigned M = (1 << BSH) - 1;

    lh[t] = 0;
    __syncthreads();
    for (int i = t; i < ecnt; i += 512)
        atomicAdd(&lh[ebuf[ebase + i] & M], 1);
    __syncthreads();

    int v = lh[t];
    lx[t] = v;
    __syncthreads();
    for (int off = 1; off < 512; off <<= 1) {
        int x = (t >= off) ? lx[t - off] : 0;
        __syncthreads();
        lx[t] += x;
        __syncthreads();
    }
    const int excl = lx[t] - v;
    {
        int n = n0 + t;
        if (n < N_) rowptr[n] = ebase + excl;
    }
    if (b == NB - 1 && t == 0) rowptr[N_] = eend;
    __syncthreads();
    lh[t] = excl;
    __syncthreads();
    for (int i = t; i < ecnt; i += 512) {
        unsigned p = ebuf[ebase + i];
        int r = atomicAdd(&lh[p & M], 1);
        nbr[ebase + r] = (int)(p >> BSH);
    }
}

// ---------------------------------------------------------------------------
// Fused GIN layer (R14, unchanged): 2-deep pipelined running-sum gather ->
// MFMA MLP -> BN -> hb slice + fused pool.
// ---------------------------------------------------------------------------
#define SWZ(row, byte) ((byte) ^ (((row) & 7) << 4))

#define GSTEP(VCUR, VNXT)                                                     \
    _Pragma("unroll")                                                         \
    for (int u = 0; u < 16; ++u)                                              \
        VNXT[u] = bf2f(*(const unsigned short*)(hbase + (unsigned)idx[u] * (unsigned)RSB + lane2)); \
    _Pragma("unroll")                                                         \
    for (int u = 0; u < 16; ++u) idx[u] = nbp[k + 32 + u];                    \
    {                                                                         \
        float runk = run;                                                     \
        _Pragma("unroll")                                                     \
        for (int u = 0; u < 16; ++u) run += VCUR[u];                          \
        if ((unsigned)(e1 - k) < 16u) { float tt = runk;                      \
            _Pragma("unroll")                                                 \
            for (int u = 0; u < 16; ++u) tt += (u < e1 - k) ? VCUR[u] : 0.f;  \
            s0 = tt; }                                                        \
        if ((unsigned)(e2 - k) < 16u) { float tt = runk;                      \
            _Pragma("unroll")                                                 \
            for (int u = 0; u < 16; ++u) tt += (u < e2 - k) ? VCUR[u] : 0.f;  \
            s1 = tt; }                                                        \
        if ((unsigned)(e3 - k) < 16u) { float tt = runk;                      \
            _Pragma("unroll")                                                 \
            for (int u = 0; u < 16; ++u) tt += (u < e3 - k) ? VCUR[u] : 0.f;  \
            s2 = tt; }                                                        \
        if ((unsigned)(cnt - k) < 16u) { float tt = runk;                     \
            _Pragma("unroll")                                                 \
            for (int u = 0; u < 16; ++u) tt += (u < cnt - k) ? VCUR[u] : 0.f; \
            s3 = tt; }                                                        \
    }                                                                         \
    k += 16;                                                                  \
    if (k > cnt) break;

template<int K>
__global__ __launch_bounds__(512) void gin_fused(
    const unsigned short* __restrict__ hin_b,  // bf16 rows: stride DD (K=64) / 32 (K=32)
    const int* __restrict__ rowptr, const int* __restrict__ nbr,
    const unsigned short* __restrict__ W1p, const float* __restrict__ b1,
    const unsigned short* __restrict__ W2p, const float* __restrict__ b2,
    const float* __restrict__ gamma, const float* __restrict__ beta,
    const float* __restrict__ mean, const float* __restrict__ var,
    const float* __restrict__ eps_p,
    __hip_bfloat16* __restrict__ out_b,        // slice ptr, stride DD
    const int* __restrict__ batch, float* __restrict__ gsum, int soff,
    int N_) {
    __shared__ char s_agg[32 * 128];   // bf16 [32 nodes][64 k], XOR-swizzled
    __shared__ char s_h1[32 * 128];
    __shared__ char s_out[32 * 128];
    __shared__ int sb[32];

    const int t = threadIdx.x;
    const int lane = t & 63;
    const int w = t >> 6;
    const int node0 = blockIdx.x * 32;
    const int nb = w * 4;

    if (t < 32) sb[t] = (node0 + t < N_) ? batch[node0 + t] : -1;

    const float eps1 = 1.0f + eps_p[0];

    // ---- combined-span gather for this wave's 4 consecutive nodes ----
    const int n0w = node0 + nb;
    const int rp0 = __builtin_amdgcn_readfirstlane(rowptr[min(n0w + 0, N_)]);
    const int rp1 = __builtin_amdgcn_readfirstlane(rowptr[min(n0w + 1, N_)]);
    const int rp2 = __builtin_amdgcn_readfirstlane(rowptr[min(n0w + 2, N_)]);
    const int rp3 = __builtin_amdgcn_readfirstlane(rowptr[min(n0w + 3, N_)]);
    const int rp4 = __builtin_amdgcn_readfirstlane(rowptr[min(n0w + 4, N_)]);
    const int cnt = rp4 - rp0;
    const int e1 = rp1 - rp0, e2 = rp2 - rp0, e3 = rp3 - rp0;
    const int* nbp = nbr + rp0;

    const int RSB = (K == 64) ? DD * 2 : 64;       // gather row stride (bytes)
    const int OST = (K == 64) ? DD : 32;           // own-row stride (elems)
    const char* hbase = (const char*)hin_b;
    const unsigned lane2 = (unsigned)(lane & (K - 1)) * 2u;

    int idx[16];
    float vA[16], vB[16];
    float run = 0.f, s0 = 0.f, s1 = 0.f, s2 = 0.f, s3 = 0.f;
    #pragma unroll
    for (int u = 0; u < 16; ++u) idx[u] = nbp[u];
    #pragma unroll
    for (int u = 0; u < 16; ++u)
        vA[u] = bf2f(*(const unsigned short*)(hbase + (unsigned)idx[u] * (unsigned)RSB + lane2));
    #pragma unroll
    for (int u = 0; u < 16; ++u) idx[u] = nbp[16 + u];
    for (int k = 0;;) {
        GSTEP(vA, vB)
        GSTEP(vB, vA)
    }
    float a0 = s0, a1 = s1 - s0, a2 = s2 - s1, a3 = s3 - s2;
    {
        const unsigned short* hbp = hin_b + (lane & (K - 1));
        if (n0w + 0 < N_) a0 += eps1 * bf2f(hbp[(size_t)(n0w + 0) * OST]);
        if (n0w + 1 < N_) a1 += eps1 * bf2f(hbp[(size_t)(n0w + 1) * OST]);
        if (n0w + 2 < N_) a2 += eps1 * bf2f(hbp[(size_t)(n0w + 2) * OST]);
        if (n0w + 3 < N_) a3 += eps1 * bf2f(hbp[(size_t)(n0w + 3) * OST]);
    }
    if (K == 64 || lane < 32) {
        const int kd = lane & (K - 1);
        *(unsigned short*)(s_agg + SWZ(nb + 0, (nb + 0) * 128 + kd * 2)) = f2bf_u(a0);
        *(unsigned short*)(s_agg + SWZ(nb + 1, (nb + 1) * 128 + kd * 2)) = f2bf_u(a1);
        *(unsigned short*)(s_agg + SWZ(nb + 2, (nb + 2) * 128 + kd * 2)) = f2bf_u(a2);
        *(unsigned short*)(s_agg + SWZ(nb + 3, (nb + 3) * 128 + kd * 2)) = f2bf_u(a3);
    }
    __syncthreads();

    // ---- GEMM1: [32 x K] @ [K x 64] via MFMA; wave w -> C tile (mt, nt) ----
    const int mt = w >> 2, nt = w & 3;
    const int arow = mt * 16 + (lane & 15);
    const int col = nt * 16 + (lane & 15);
    f32x4 c1v = (f32x4){0.f, 0.f, 0.f, 0.f};
    #pragma unroll
    for (int ks = 0; ks < K / 32; ++ks) {
        bf16x8 a = *(const bf16x8*)(s_agg + SWZ(arow, arow * 128 + ks * 64 + ((lane >> 4) << 4)));
        bf16x8 b = *(const bf16x8*)(W1p + (((ks << 2) + nt) << 9) + (lane << 3));
        c1v = __builtin_amdgcn_mfma_f32_16x16x32_bf16(a, b, c1v, 0, 0, 0);
    }
    {
        const float bb1 = b1[col];
        #pragma unroll
        for (int reg = 0; reg < 4; ++reg) {
            int row = mt * 16 + ((lane >> 4) << 2) + reg;
            float v = fmaxf(c1v[reg] + bb1, 0.f);
            *(unsigned short*)(s_h1 + SWZ(row, row * 128 + col * 2)) = f2bf_u(v);
        }
    }
    __syncthreads();

    // ---- GEMM2: [32 x 64] @ [64 x 64] + BN epilogue ----
    f32x4 c2v = (f32x4){0.f, 0.f, 0.f, 0.f};
    #pragma unroll
    for (int ks = 0; ks < 2; ++ks) {
        bf16x8 a = *(const bf16x8*)(s_h1 + SWZ(arow, arow * 128 + ks * 64 + ((lane >> 4) << 4)));
        bf16x8 b = *(const bf16x8*)(W2p + (((ks << 2) + nt) << 9) + (lane << 3));
        c2v = __builtin_amdgcn_mfma_f32_16x16x32_bf16(a, b, c2v, 0, 0, 0);
    }
    {
        const float bb2 = b2[col];
        const float ga = gamma[col], bet = beta[col], mu = mean[col];
        const float iv = rsqrtf(var[col] + 1e-5f);
        #pragma unroll
        for (int reg = 0; reg < 4; ++reg) {
            int row = mt * 16 + ((lane >> 4) << 2) + reg;
            float v = fmaxf(c2v[reg] + bb2, 0.f);
            v = ga * (v - mu) * iv + bet;
            *(unsigned short*)(s_out + SWZ(row, row * 128 + col * 2)) = f2bf_u(v);
        }
    }
    __syncthreads();

    // ---- coalesced copy out: 32 rows x 128B, 16 threads/row x 8B ----
    {
        int r = t >> 4, c8 = t & 15;
        int node = node0 + r;
        if (node < N_) {
            ushort4 v = *(const ushort4*)(s_out + SWZ(r, r * 128 + c8 * 8));
            *(ushort4*)((unsigned short*)out_b + (size_t)node * DD + c8 * 4) = v;
        }
    }

    // ---- fused mean-pool accumulation for this slice (batch sorted) ----
    if (t < 256) {
        const int d = t & 63;
        const int rg = t >> 6;
        float acc = 0.f;
        int curg = sb[rg * 8];
        #pragma unroll
        for (int r = rg * 8; r < rg * 8 + 8; ++r) {
            int g = sb[r];
            if (g != curg) {
                if (curg >= 0) atomicAdd(&gsum[curg * DD + soff + d], acc);
                acc = 0.f; curg = g;
            }
            if (g >= 0)
                acc += bf2f(*(const unsigned short*)(s_out + SWZ(r, r * 128 + d * 2)));
        }
        if (curg >= 0) atomicAdd(&gsum[curg * DD + soff + d], acc);
    }
}

// ---------------------------------------------------------------------------
// Classification head: one block per graph (fp32 throughout).
// ---------------------------------------------------------------------------
__global__ void head_kernel(const float* __restrict__ gsum, const int* __restrict__ gcnt_i,
                            const float* __restrict__ W1, const float* __restrict__ b1,
                            const float* __restrict__ W2, const float* __restrict__ b2,
                            const float* __restrict__ W3, const float* __restrict__ b3,
                            const float* __restrict__ W4, const float* __restrict__ b4,
                            float* __restrict__ class_out, int* __restrict__ comp_idx) {
    const int g = blockIdx.x;
    const int t = threadIdx.x;
    __shared__ float ge[DD], h1[128], h2[64], h3[64], logits[NCC];

    const float c = fmaxf((float)gcnt_i[g], 1.0f);
    if (t < DD) ge[t] = gsum[g * DD + t] / c;
    __syncthreads();

    if (t < 128) {
        float a = b1[t];
        #pragma unroll 4
        for (int k = 0; k < DD; ++k) a += ge[k] * W1[k * 128 + t];
        h1[t] = fmaxf(a, 0.0f);
    }
    __syncthreads();
    if (t < 64) {
        float a = b2[t];
        #pragma unroll 4
        for (int k = 0; k < 128; ++k) a += h1[k] * W2[k * 64 + t];
        h2[t] = fmaxf(a, 0.0f);
    }
    __syncthreads();
    if (t < 64) {
        float a = b3[t];
        #pragma unroll 4
        for (int k = 0; k < 64; ++k) a += h2[k] * W3[k * 64 + t];
        h3[t] = fmaxf(a, 0.0f);
    }
    __syncthreads();
    if (t < NCC) {
        float a = b4[t];
        #pragma unroll
        for (int k = 0; k < 64; ++k) a += h3[k] * W4[k * NCC + t];
        logits[t] = a;
    }
    __syncthreads();
    if (t == 0) {
        float mx = logits[0]; int am = 0;
        for (int j = 1; j < NCC; ++j) if (logits[j] > mx) { mx = logits[j]; am = j; }
        float se = 0.0f;
        for (int j = 0; j < NCC; ++j) se += expf(logits[j] - mx);
        float lse = logf(se);
        for (int j = 0; j < NCC; ++j) class_out[g * NCC + j] = logits[j] - mx - lse;
        comp_idx[g] = am;
    }
}

// ---------------------------------------------------------------------------
// edge_mfma (R10, unchanged): 64 candidates / 256-thread block, col-split.
// ---------------------------------------------------------------------------
__global__ __launch_bounds__(256, 5) void edge_mfma(
    const int* __restrict__ cand, const int* __restrict__ batch,
    const int* __restrict__ comp_idx, const short* __restrict__ hb,
    const unsigned short* __restrict__ W1b_p, const unsigned short* __restrict__ W2_p,
    const float* __restrict__ pc, const float* __restrict__ W3,
    const float* __restrict__ b3, float* __restrict__ scores, int C_) {
    __shared__ char s_buf[64 * 384];   // de (24KB); h1 reuses first 16KB
    __shared__ float s_part[4][64];
    __shared__ int s_node[64];
    __shared__ int s_ci[64];
    __shared__ float s_w3[64];

    const int t = threadIdx.x;
    const int lane = t & 63;
    const int w = t >> 6;
    const int c0 = blockIdx.x * 64;

    if (t < 64) {
        int c = c0 + t;
        int node = (c < C_) ? cand[c] : cand[0];
        s_node[t] = node;
        s_ci[t] = comp_idx[batch[node]];
        s_w3[t] = W3[t];
    }
    __syncthreads();

    for (int i = t; i < 64 * 24; i += 256) {
        int r = i / 24, c8 = i - r * 24;
        bf16x8 v = *(const bf16x8*)(hb + (size_t)s_node[r] * DD + c8 * 8);
        *(bf16x8*)(s_buf + SWZ(r, r * 384 + c8 * 16)) = v;
    }
    __syncthreads();

    f32x4 acc1[4][2];
    #pragma unroll
    for (int rt = 0; rt < 4; ++rt)
        #pragma unroll
        for (int b = 0; b < 2; ++b) acc1[rt][b] = (f32x4){0.f, 0.f, 0.f, 0.f};
    #pragma unroll
    for (int ks = 0; ks < 6; ++ks) {
        bf16x8 b0 = *(const bf16x8*)(W1b_p + ((ks * 8 + 2 * w + 0) << 9) + (lane << 3));
        bf16x8 b1f = *(const bf16x8*)(W1b_p + ((ks * 8 + 2 * w + 1) << 9) + (lane << 3));
        #pragma unroll
        for (int rt = 0; rt < 4; ++rt) {
            int arow = rt * 16 + (lane & 15);
            bf16x8 a = *(const bf16x8*)(s_buf + SWZ(arow, arow * 384 + ks * 64 + ((lane >> 4) << 4)));
            acc1[rt][0] = __builtin_amdgcn_mfma_f32_16x16x32_bf16(a, b0, acc1[rt][0], 0, 0, 0);
            acc1[rt][1] = __builtin_amdgcn_mfma_f32_16x16x32_bf16(a, b1f, acc1[rt][1], 0, 0, 0);
        }
    }
    __syncthreads();

    #pragma unroll
    for (int rt = 0; rt < 4; ++rt) {
        #pragma unroll
        for (int reg = 0; reg < 4; ++reg) {
            int row = rt * 16 + ((lane >> 4) << 2) + reg;
            int ci = s_ci[row];
            #pragma unroll
            for (int b = 0; b < 2; ++b) {
                int col = (2 * w + b) * 16 + (lane & 15);
                float v = fmaxf(acc1[rt][b][reg] + pc[ci * 128 + col], 0.f);
                *(unsigned short*)(s_buf + SWZ(row, row * 256 + col * 2)) = f2bf_u(v);
            }
        }
    }
    __syncthreads();

    f32x4 acc2[4];
    #pragma unroll
    for (int rt = 0; rt < 4; ++rt) acc2[rt] = (f32x4){0.f, 0.f, 0.f, 0.f};
    #pragma unroll
    for (int ks = 0; ks < 4; ++ks) {
        bf16x8 b = *(const bf16x8*)(W2_p + ((ks * 4 + w) << 9) + (lane << 3));
        #pragma unroll
        for (int rt = 0; rt < 4; ++rt) {
            int arow = rt * 16 + (lane & 15);
            bf16x8 a = *(const bf16x8*)(s_buf + SWZ(arow, arow * 256 + ks * 64 + ((lane >> 4) << 4)));
            acc2[rt] = __builtin_amdgcn_mfma_f32_16x16x32_bf16(a, b, acc2[rt], 0, 0, 0);
        }
    }

    {
        const float w3v = s_w3[w * 16 + (lane & 15)];
        #pragma unroll
        for (int rt = 0; rt < 4; ++rt) {
            #pragma unroll
            for (int reg = 0; reg < 4; ++reg) {
                float p = fmaxf(acc2[rt][reg], 0.f) * w3v;
                p += __shfl_xor(p, 1);
                p += __shfl_xor(p, 2);
                p += __shfl_xor(p, 4);
                p += __shfl_xor(p, 8);
                if ((lane & 15) == 0)
                    s_part[w][rt * 16 + ((lane >> 4) << 2) + reg] = p;
            }
        }
    }
    __syncthreads();

    if (t < 64) {
        int c = c0 + t;
        if (c < C_) {
            float p = s_part[0][t] + s_part[1][t] + s_part[2][t] + s_part[3][t] + b3[0];
            scores[c] = 1.0f / (1.0f + expf(-p));
        }
    }
}

// ---------------------------------------------------------------------------
extern "C" void kernel_launch(void* const* d_in, const int* in_sizes, int n_in,
                              void* d_out, int out_size, void* d_ws, size_t ws_size,
                              hipStream_t stream) {
    const float* x        = (const float*)d_in[0];
    const int*   ei       = (const int*)d_in[1];
    const int*   batch    = (const int*)d_in[2];
    const int*   cand     = (const int*)d_in[3];
    const float* c1_W1    = (const float*)d_in[4];
    const float* c1_b1    = (const float*)d_in[5];
    const float* c1_W2    = (const float*)d_in[6];
    const float* c1_b2    = (const float*)d_in[7];
    const float* c1_g     = (const float*)d_in[8];
    const float* c1_be    = (const float*)d_in[9];
    const float* c1_m     = (const float*)d_in[10];
    const float* c1_v     = (const float*)d_in[11];
    const float* c1_eps   = (const float*)d_in[12];
    const float* cs_W1    = (const float*)d_in[13];
    const float* cs_b1    = (const float*)d_in[14];
    const float* cs_W2    = (const float*)d_in[15];
    const float* cs_b2    = (const float*)d_in[16];
    const float* cs_g     = (const float*)d_in[17];
    const float* cs_be    = (const float*)d_in[18];
    const float* cs_m     = (const float*)d_in[19];
    const float* cs_v     = (const float*)d_in[20];
    const float* cs_eps   = (const float*)d_in[21];
    const float* nc_W1    = (const float*)d_in[22];
    const float* nc_b1    = (const float*)d_in[23];
    const float* nc_W2    = (const float*)d_in[24];
    const float* nc_b2    = (const float*)d_in[25];
    const float* nc_W3    = (const float*)d_in[26];
    const float* nc_b3    = (const float*)d_in[27];
    const float* nc_W4    = (const float*)d_in[28];
    const float* nc_b4    = (const float*)d_in[29];
    const float* comp_emb = (const float*)d_in[30];
    const float* ep_W1    = (const float*)d_in[31];
    const float* ep_b1    = (const float*)d_in[32];
    const float* ep_W2    = (const float*)d_in[33];
    const float* ep_b2    = (const float*)d_in[34];
    const float* ep_W3    = (const float*)d_in[35];
    const float* ep_b3    = (const float*)d_in[36];

    const int N_ = in_sizes[0] / 32;
    const int E_ = in_sizes[1] / 2;
    const int C_ = in_sizes[3];
    const int* src = ei;
    const int* dst = ei + E_;
    const int NB = (N_ + (1 << BSH) - 1) >> BSH;   // 196 buckets of 512 nodes

    char* ws = (char*)d_ws;
    size_t off = 0;
    __hip_bfloat16* hb = (__hip_bfloat16*)(ws + off); off += (size_t)N_ * DD * 2;
    unsigned short* xb = (unsigned short*)(ws + off); off += (size_t)N_ * 32 * 2;
    int*   rowptr   = (int*)(ws + off);   off += (size_t)(N_ + 2) * 4;
    int*   nbr      = (int*)(ws + off);   off += (size_t)(E_ + 128) * 4;
    int*   hist_part= (int*)(ws + off);   off += (size_t)HI_BLK * 512 * 4;
    int*   bbase    = (int*)(ws + off);   off += 2080;
    int*   bpos     = (int*)(ws + off);   off += 2048;
    float* gsum     = (float*)(ws + off); off += (size_t)GG * DD * 4;
    int*   gcnt_i   = (int*)(ws + off);   off += 1024;
    int*   comp_idx = (int*)(ws + off);   off += 1024;
    float* pc       = (float*)(ws + off); off += NCC * 128 * 4;
    unsigned short* W1b_p = (unsigned short*)(ws + off); off += 6 * 8 * 512 * 2;
    unsigned short* W2_p  = (unsigned short*)(ws + off); off += 4 * 4 * 512 * 2;
    unsigned short* enc   = (unsigned short*)(ws + off); off += 22528 * 2;
    // ebuf (E x 4B = 4.8MB) aliases hb: fully consumed by csr_bucket before
    // the first gin_fused writes hb (same stream, serial).
    unsigned* ebuf  = (unsigned*)hb;

    float* class_out = (float*)d_out;
    float* scores    = class_out + GG * NCC;

    // ---- fused prep: weight packing + x2b + private histograms (1 launch) ----
    prep_all<<<PE_BLK + EN_BLK + XB_BLK + HI_BLK + 1, 256, 0, stream>>>(
        ep_W1, ep_b1, ep_W2, comp_emb, W1b_p, W2_p, pc,
        c1_W1, c1_W2, cs_W1, cs_W2, enc,
        x, xb, N_ * 32 / 4, dst, E_, hist_part, nbr + E_);

    // ---- binned CSR build ----
    scan_misc<<<2 + (GG * DD + 255) / 256, 256, 0, stream>>>(
        hist_part, bbase, bpos, NB, E_, batch, gcnt_i, gsum, N_);
    bin_scatter<<<(E_ + 4095) / 4096, 256, 0, stream>>>(src, dst, bpos, ebuf, E_);
    csr_bucket<<<NB, 512, 0, stream>>>(ebuf, bbase, rowptr, nbr, N_, NB);

    // ---- GIN layers (fused gather + MFMA MLP + fused pool) ----
    const int gblk = (N_ + 31) / 32;
    gin_fused<32><<<gblk, 512, 0, stream>>>(
        xb, rowptr, nbr,
        enc + 0, c1_b1, enc + 2048, c1_b2,
        c1_g, c1_be, c1_m, c1_v, c1_eps, hb + 0, batch, gsum, 0, N_);
    gin_fused<64><<<gblk, 512, 0, stream>>>(
        (const unsigned short*)hb + 0, rowptr, nbr,
        enc + 6144, cs_b1 + 0, enc + 10240, cs_b2 + 0,
        cs_g + 0, cs_be + 0, cs_m + 0, cs_v + 0, cs_eps + 0, hb + 64, batch, gsum, 64, N_);
    gin_fused<64><<<gblk, 512, 0, stream>>>(
        (const unsigned short*)hb + 64, rowptr, nbr,
        enc + 14336, cs_b1 + 64, enc + 18432, cs_b2 + 64,
        cs_g + 64, cs_be + 64, cs_m + 64, cs_v + 64, cs_eps + 1, hb + 128, batch, gsum, 128, N_);

    // ---- head ----
    head_kernel<<<GG, 256, 0, stream>>>(gsum, gcnt_i, nc_W1, nc_b1, nc_W2, nc_b2,
                                        nc_W3, nc_b3, nc_W4, nc_b4, class_out, comp_idx);

    // ---- edge prediction (MFMA) ----
    edge_mfma<<<(C_ + 63) / 64, 256, 0, stream>>>(
        cand, batch, comp_idx, (const short*)hb, W1b_p, W2_p, pc, ep_W3, ep_b3, scores, C_);
}